// Round 15
// baseline (358.452 us; speedup 1.0000x reference)
//
#include <hip/hip_runtime.h>
#include <hip/hip_fp16.h>
#include <math.h>

#define NB 32
#define NTOK 4096
#define DIM 256
#define NS 8
#define HID 512
#define NCHUNK 64
#define LN_EPS 1e-5f
#define ATT_EPS 1e-8f
#define SCALE 0.0625f
#define NROWS (NB * NS)   // 256

// ---- cross-lane primitives (VALU-pipe: DPP / permlane) ---------------------
#define DPPF(x, ctrl) __int_as_float(__builtin_amdgcn_update_dpp(0, __float_as_int(x), (ctrl), 0xF, 0xF, true))
// 0xB1 quad_perm xor1, 0x4E quad_perm xor2, 0x141 row_half_mirror (xor7),
// 0x124 row_ror:4, 0x128 row_ror:8

__device__ __forceinline__ float addx16(float c) {
#if __has_builtin(__builtin_amdgcn_permlane16_swap)
    auto r = __builtin_amdgcn_permlane16_swap(__float_as_uint(c), __float_as_uint(c), false, false);
    return __uint_as_float(r[0]) + __uint_as_float(r[1]);
#else
    return c + __shfl_xor(c, 16);
#endif
}
__device__ __forceinline__ float addx32(float c) {
#if __has_builtin(__builtin_amdgcn_permlane32_swap)
    auto r = __builtin_amdgcn_permlane32_swap(__float_as_uint(c), __float_as_uint(c), false, false);
    return __uint_as_float(r[0]) + __uint_as_float(r[1]);
#else
    return c + __shfl_xor(c, 32);
#endif
}

// sum + sumsq over 64 lanes, both results in every lane.
__device__ __forceinline__ void tree2(float v0, float v1, int lane, float& S, float& Q) {
    bool hi = lane & 1;
    float send = hi ? v0 : v1;
    float recv = DPPF(send, 0xB1);
    float a = (hi ? v1 : v0) + recv;
    a += DPPF(a, 0x4E);
    a += DPPF(a, 0x124);
    a += DPPF(a, 0x128);
    a = addx16(a);
    a = addx32(a);
    float other = DPPF(a, 0xB1);
    S = hi ? other : a;
    Q = hi ? a : other;
}

// sum + sumsq over each 32-lane half-wave, both results in every lane of half.
__device__ __forceinline__ void tree2h(float v0, float v1, int lane, float& S, float& Q) {
    bool hi = lane & 1;
    float send = hi ? v0 : v1;
    float recv = DPPF(send, 0xB1);
    float a = (hi ? v1 : v0) + recv;
    a += DPPF(a, 0x4E);
    a += DPPF(a, 0x124);
    a += DPPF(a, 0x128);
    a = addx16(a);
    float other = DPPF(a, 0xB1);
    S = hi ? other : a;
    Q = hi ? a : other;
}

// 8 independent sums over a 32-lane half-wave; lane ends with full half-wave
// sum of slot sig(lane) = (l0<<2)|(l1<<1)|(l0^l1^l2).
__device__ __forceinline__ float tree8h(const float v[8], int lane) {
    bool b0 = lane & 1;
    bool b1 = lane & 2;
    bool bp = ((lane ^ (lane >> 1) ^ (lane >> 2)) & 1);
    float a[4];
#pragma unroll
    for (int j = 0; j < 4; j++) {
        float send = b0 ? v[j] : v[4 + j];
        float recv = DPPF(send, 0xB1);
        a[j] = (b0 ? v[4 + j] : v[j]) + recv;
    }
    float b[2];
#pragma unroll
    for (int j = 0; j < 2; j++) {
        float send = b1 ? a[j] : a[2 + j];
        float recv = DPPF(send, 0x4E);
        b[j] = (b1 ? a[2 + j] : a[j]) + recv;
    }
    float send = bp ? b[0] : b[1];
    float recv = DPPF(send, 0x141);
    float c = (bp ? b[1] : b[0]) + recv;
    c += DPPF(c, 0x128);
    c = addx16(c);
    return c;
}

typedef _Float16 h2v __attribute__((ext_vector_type(2)));
typedef float f32x2 __attribute__((ext_vector_type(2)));
__device__ __forceinline__ float fdot2u(unsigned a, unsigned b, float c) {
#if __has_builtin(__builtin_amdgcn_fdot2)
    return __builtin_amdgcn_fdot2(__builtin_bit_cast(h2v, a), __builtin_bit_cast(h2v, b), c, false);
#else
    __half2 ha = __builtin_bit_cast(__half2, a), hb = __builtin_bit_cast(__half2, b);
    return c + __low2float(ha) * __low2float(hb) + __high2float(ha) * __high2float(hb);
#endif
}
__device__ __forceinline__ unsigned pkh(float a, float b) {
    return __builtin_bit_cast(unsigned, __floats2half2_rn(a, b));
}
__device__ __forceinline__ float2 h2f2(unsigned u) {
    __half2 h = __builtin_bit_cast(__half2, u);
    return float2{__low2float(h), __high2float(h)};
}
__device__ __forceinline__ f32x2 h2f2v(unsigned u) {
    __half2 h = __builtin_bit_cast(__half2, u);
    return f32x2{__low2float(h), __high2float(h)};
}
// packed 2x f32 FMA: acc = a*b + acc  (CDNA v_pk_fma_f32, full-rate)
__device__ __forceinline__ void pkfma(f32x2& acc, f32x2 a, f32x2 b) {
    asm("v_pk_fma_f32 %0, %1, %2, %0" : "+v"(acc) : "v"(a), "v"(b));
}

// ================= K1: weight prep (role-switched) ===========================
#define WP_BIAS  128
#define WP_WHH0  129
#define WP_F1H0  225
#define WP_F2H0  289
#define WP_W2C0  353
#define WP_F1B0  401
#define WP_B2G0  403
#define WP_BLKS  406

__global__ void __launch_bounds__(256)
k_pre(const float* __restrict__ wq, const float* __restrict__ wk,
      const float* __restrict__ bk, const float* __restrict__ bq,
      const float* __restrict__ lsb, const float* __restrict__ lsw,
      unsigned* __restrict__ MppH, float* __restrict__ u2p, float* __restrict__ biasp,
      const float* __restrict__ wv, const float* __restrict__ wih,
      unsigned* __restrict__ w2cH,
      const float* __restrict__ f1w, const float* __restrict__ f1b,
      const float* __restrict__ lfb, float* __restrict__ f1bp,
      const float* __restrict__ bih, const float* __restrict__ bv,
      float* __restrict__ b2g,
      const float* __restrict__ whh, const float* __restrict__ f2w,
      const float* __restrict__ lfw,
      unsigned* __restrict__ whhH, unsigned* __restrict__ f1H,
      unsigned* __restrict__ f2H) {
    int bid = blockIdx.x, t = threadIdx.x;

    if (bid < WP_BIAS) {                       // ---- MppH: e-pair (2b, 2b+1)
        int b = bid, o = t;
        float a0 = 0.f, a1 = 0.f;
        for (int d = 0; d < 256; d++) {
            float2 wqp = *(const float2*)&wq[(size_t)d * 256 + 2 * b];
            float wkv = wk[(size_t)d * 256 + o];
            a0 = fmaf(wqp.x, wkv, a0);
            a1 = fmaf(wqp.y, wkv, a1);
        }
        MppH[(size_t)b * 256 + o] = pkh(a0 * lsw[2 * b], a1 * lsw[2 * b + 1]);
        return;
    }
    if (bid == WP_BIAS) {                      // ---- biasp / u2p / k2
        int o = t;
        __shared__ float t2l[256], bkl[256], red[4];
        bkl[o] = bk[o];
        float a = bq[o];
        for (int k = 0; k < 256; k++) a = fmaf(wq[(size_t)o * 256 + k], lsb[k], a);
        t2l[o] = a;
        __syncthreads();
        float ab = 0.f, au = 0.f;
        for (int d = 0; d < 256; d++) {
            ab = fmaf(t2l[d], wk[(size_t)d * 256 + o], ab);
            au = fmaf(bkl[d], wq[(size_t)d * 256 + o], au);
        }
        biasp[o] = ab;
        u2p[o] = au * lsw[o];
        float kk = t2l[o] * bkl[o];
        kk += DPPF(kk, 0xB1);
        kk += DPPF(kk, 0x4E);
        kk += DPPF(kk, 0x124);
        kk += DPPF(kk, 0x128);
        kk = addx16(kk);
        kk = addx32(kk);
        if ((t & 63) == 0) red[t >> 6] = kk;
        __syncthreads();
        if (t == 0) biasp[256] = red[0] + red[1] + red[2] + red[3];
        return;
    }
    if (bid < WP_W2C0) {                       // ---- transpose-pack roles
        const float* in; unsigned* out; const float* scl = nullptr;
        int C, OS, r, RT;
        if (bid < WP_F1H0)      { in = whh; out = whhH; C = 256; OS = 768; r = bid - WP_WHH0; RT = 24; }
        else if (bid < WP_F2H0) { in = f1w; out = f1H;  C = 256; OS = 512; r = bid - WP_F1H0; RT = 16; scl = lfw; }
        else                    { in = f2w; out = f2H;  C = 512; OS = 256; r = bid - WP_F2H0; RT = 8; }
        int otl = r % RT, ept = r / RT;
        __shared__ float tile[32][65];
#pragma unroll
        for (int i = 0; i < 8; i++) {
            int idx = t + i * 256;
            int row = idx >> 6, col = idx & 63;
            tile[row][col] = in[(size_t)(otl * 32 + row) * C + ept * 64 + col];
        }
        __syncthreads();
#pragma unroll
        for (int i = 0; i < 4; i++) {
            int idx = t + i * 256;
            int epl = idx >> 5, ol = idx & 31;
            float v0 = tile[ol][2 * epl], v1 = tile[ol][2 * epl + 1];
            if (scl) { v0 *= scl[ept * 64 + 2 * epl]; v1 *= scl[ept * 64 + 2 * epl + 1]; }
            out[(size_t)(ept * 32 + epl) * OS + otl * 32 + ol] = pkh(v0, v1);
        }
        return;
    }
    if (bid < WP_F1B0) {                       // ---- w2cH
        int r = bid - WP_W2C0;
        int et = r & 3, ot = r >> 2;
        int ep = et * 32 + (t & 31), og = (t >> 5) * 8;
        float alo[8] = {}, ahi[8] = {};
        for (int d = 0; d < 256; d++) {
            float2 wvp = *(const float2*)&wv[(size_t)d * 256 + 2 * ep];
#pragma unroll
            for (int i = 0; i < 8; i++) {
                float wv_ih = wih[(size_t)(ot * 64 + og + i) * 256 + d];
                alo[i] = fmaf(wvp.x, wv_ih, alo[i]);
                ahi[i] = fmaf(wvp.y, wv_ih, ahi[i]);
            }
        }
#pragma unroll
        for (int i = 0; i < 8; i++)
            w2cH[(size_t)ep * 768 + ot * 64 + og + i] = pkh(alo[i], ahi[i]);
        return;
    }
    if (bid < WP_B2G0) {                       // ---- f1bp
        int h = (bid - WP_F1B0) * 256 + t;
        float a = f1b[h];
        for (int e = 0; e < 256; e++) a = fmaf(f1w[(size_t)h * 256 + e], lfb[e], a);
        f1bp[h] = a;
        return;
    }
    {                                          // ---- b2g
        int o = (bid - WP_B2G0) * 256 + t;
        float a = bih[o];
        for (int d = 0; d < 256; d++) a = fmaf(wih[(size_t)o * 256 + d], bv[d], a);
        b2g[o] = a;
    }
}

// ================= K2: slots init + first qk =================================
__global__ void __launch_bounds__(512)
k_iq(const float* __restrict__ noise, const float* __restrict__ mu,
     const float* __restrict__ sg, float* __restrict__ slots,
     const unsigned* __restrict__ MppH, const float* __restrict__ biasp,
     const float* __restrict__ u2p,
     float* __restrict__ qkw, float* __restrict__ c2b) {
    int bb = blockIdx.x, t = threadIdx.x, wave = t >> 6, lane = t & 63;
    __shared__ float S2[NS][DIM], Zl[NS][DIM];
#pragma unroll
    for (int k = 0; k < 4; k++) {
        int idx = k * 512 + t, d = idx & 255;
        float v = mu[d] + sg[d] * noise[(size_t)bb * 2048 + idx];
        S2[idx >> 8][d] = v;
        slots[(size_t)bb * 2048 + idx] = v;
    }
    __syncthreads();
    {
        float4 xv = *(const float4*)&S2[wave][lane * 4];
        float S, Q;
        tree2(xv.x + xv.y + xv.z + xv.w,
              xv.x * xv.x + xv.y * xv.y + xv.z * xv.z + xv.w * xv.w, lane, S, Q);
        float m = S * (1.f / DIM);
        float rstd = rsqrtf(Q * (1.f / DIM) - m * m + LN_EPS);
        Zl[wave][lane * 4 + 0] = (xv.x - m) * rstd;
        Zl[wave][lane * 4 + 1] = (xv.y - m) * rstd;
        Zl[wave][lane * 4 + 2] = (xv.z - m) * rstd;
        Zl[wave][lane * 4 + 3] = (xv.w - m) * rstd;
    }
    __syncthreads();
    int o = t & 255, sg2 = (t >> 8) * 4;
    float acc[4] = {};
    for (int ep = 0; ep < 128; ep++) {
        float2 wf = h2f2(MppH[(size_t)ep * 256 + o]);
#pragma unroll
        for (int i = 0; i < 4; i++) {
            float2 zp = *(const float2*)&Zl[sg2 + i][2 * ep];
            acc[i] = fmaf(zp.x, wf.x, fmaf(zp.y, wf.y, acc[i]));
        }
    }
    float bo = biasp[o];
#pragma unroll
    for (int i = 0; i < 4; i++)
        qkw[(size_t)(bb * NS + sg2 + i) * DIM + o] = acc[i] + bo;
    if (t < 64) {
        int s = t >> 3, j = t & 7;
        float a = 0.f;
        for (int e = j * 32; e < j * 32 + 32; e++) a = fmaf(Zl[s][e], u2p[e], a);
        a += DPPF(a, 0xB1);
        a += DPPF(a, 0x4E);
        a += DPPF(a, 0x141);
        if (j == 0) c2b[bb * NS + s] = a + biasp[256];
    }
}

// ================= per-iter: fused attention (64 tokens/block, deep grid) ====
// FIRST: read f32 x, inline LN -> f16 pack (also stored to xh for later iters).
// else:  read f16 xh directly.
template<bool FIRST>
__global__ void __launch_bounds__(256, 4)
k_attnT(const float* __restrict__ x, const float* __restrict__ liw,
        const float* __restrict__ lib, __half* __restrict__ xh,
        const float* __restrict__ qkw, const float* __restrict__ c2b,
        unsigned* __restrict__ puH, float* __restrict__ pda) {
    const int bb = blockIdx.x, chunk = blockIdx.y;
    const int t = threadIdx.x, wave = t >> 6, lane = t & 63;
    const int l0 = lane & 1, l1 = (lane >> 1) & 1, l2 = (lane >> 2) & 1;
    const int sig = (l0 << 2) | (l1 << 1) | (l0 ^ l1 ^ l2);
    const int e0 = (lane & 31) * 8;

    unsigned qh[NS][4];
#pragma unroll
    for (int s = 0; s < NS; s++) {
        const float4 a = *(const float4*)&qkw[(size_t)(bb * NS + s) * DIM + e0];
        const float4 b = *(const float4*)&qkw[(size_t)(bb * NS + s) * DIM + e0 + 4];
        qh[s][0] = pkh(a.x, a.y); qh[s][1] = pkh(a.z, a.w);
        qh[s][2] = pkh(b.x, b.y); qh[s][3] = pkh(b.z, b.w);
    }
    const float qbs = c2b[bb * NS + sig] * SCALE;

    f32x2 ua2[NS][4] = {};
    float da[NS] = {};

    const size_t row0 = (size_t)bb * NTOK + chunk * 64 + wave * 16 + (lane >> 5);
    const __half* xp = xh + row0 * DIM + e0;
    const float* xpf = x + row0 * DIM + e0;

    float4 wA, wB, bA, bB;
    float4 cfa, cfb;
    uint4 nxt;
    if (FIRST) {
        wA = *(const float4*)&liw[e0];
        wB = *(const float4*)&liw[e0 + 4];
        bA = *(const float4*)&lib[e0];
        bB = *(const float4*)&lib[e0 + 4];
        cfa = *(const float4*)xpf;
        cfb = *(const float4*)(xpf + 4);
    } else {
        nxt = *(const uint4*)xp;
    }

    for (int i = 0; i < 8; i++) {
        uint4 xv;
        if (FIRST) {
            float4 na, nb;
            if (i < 7) {
                na = *(const float4*)(xpf + (size_t)(i + 1) * 512);
                nb = *(const float4*)(xpf + (size_t)(i + 1) * 512 + 4);
            }
            float s1 = cfa.x + cfa.y + cfa.z + cfa.w + cfb.x + cfb.y + cfb.z + cfb.w;
            float s2 = cfa.x * cfa.x + cfa.y * cfa.y + cfa.z * cfa.z + cfa.w * cfa.w +
                       cfb.x * cfb.x + cfb.y * cfb.y + cfb.z * cfb.z + cfb.w * cfb.w;
            float S, Q;
            tree2h(s1, s2, lane, S, Q);
            float m = S * (1.f / DIM);
            float rstd = rsqrtf(Q * (1.f / DIM) - m * m + LN_EPS);
            xv.x = pkh((cfa.x - m) * rstd * wA.x + bA.x, (cfa.y - m) * rstd * wA.y + bA.y);
            xv.y = pkh((cfa.z - m) * rstd * wA.z + bA.z, (cfa.w - m) * rstd * wA.w + bA.w);
            xv.z = pkh((cfb.x - m) * rstd * wB.x + bB.x, (cfb.y - m) * rstd * wB.y + bB.y);
            xv.w = pkh((cfb.z - m) * rstd * wB.z + bB.z, (cfb.w - m) * rstd * wB.w + bB.w);
            *(uint4*)(xh + (row0 + (size_t)i * 2) * DIM + e0) = xv;
            cfa = na; cfb = nb;
        } else {
            xv = nxt;
            if (i < 7) nxt = *(const uint4*)(xp + (size_t)(i + 1) * 2 * DIM);
        }
        float dp[NS];
#pragma unroll
        for (int s = 0; s < NS; s++)
            dp[s] = fdot2u(qh[s][0], xv.x, fdot2u(qh[s][1], xv.y,
                    fdot2u(qh[s][2], xv.z, fdot2u(qh[s][3], xv.w, 0.f))));
        float ds = tree8h(dp, lane);
        float dv = fmaf(ds, SCALE, qbs);
        float mx = dv;
        mx = fmaxf(mx, DPPF(mx, 0xB1));
        mx = fmaxf(mx, DPPF(mx, 0x4E));
        mx = fmaxf(mx, DPPF(mx, 0x141));
        float e = __expf(dv - mx);
        float sm = e;
        sm += DPPF(sm, 0xB1);
        sm += DPPF(sm, 0x4E);
        sm += DPPF(sm, 0x141);
        float g0 = fmaf(e, __fdividef(1.f, sm), ATT_EPS);
        float g1 = DPPF(g0, 0x141);
        float g2 = DPPF(g0, 0x4E);
        float g3 = DPPF(g1, 0x4E);
        float g4 = DPPF(g0, 0xB1);
        float g5 = DPPF(g1, 0xB1);
        float g6 = DPPF(g2, 0xB1);
        float g7 = DPPF(g3, 0xB1);
        float gth[NS] = {g0, g1, g2, g3, g4, g5, g6, g7};
        f32x2 xd[4] = {h2f2v(xv.x), h2f2v(xv.y), h2f2v(xv.z), h2f2v(xv.w)};
#pragma unroll
        for (int j = 0; j < NS; j++) {
            float pj = gth[j];
            da[j] += pj;
            f32x2 pj2 = {pj, pj};
#pragma unroll
            for (int k = 0; k < 4; k++) pkfma(ua2[j][k], xd[k], pj2);
        }
    }
#pragma unroll
    for (int j = 0; j < NS; j++) {
        da[j] = addx32(da[j]);
#pragma unroll
        for (int k = 0; k < 4; k++) {
            ua2[j][k].x = addx32(ua2[j][k].x);
            ua2[j][k].y = addx32(ua2[j][k].y);
        }
    }
    __shared__ unsigned ulH[4][NS][128];
    __shared__ float dl[4][NS];
    const int M8[NS] = {0, 7, 3, 4, 5, 2, 6, 1};
    if (lane < 32) {
        int c0 = lane * 4;
#pragma unroll
        for (int j = 0; j < NS; j++) {
            int sj = sig ^ M8[j];
#pragma unroll
            for (int k = 0; k < 4; k++)
                ulH[wave][sj][c0 + k] = pkh(ua2[j][k].x, ua2[j][k].y);
        }
    }
    if (lane < 8) {
#pragma unroll
        for (int j = 0; j < NS; j++) dl[wave][sig ^ M8[j]] = da[j];
    }
    __syncthreads();
    size_t base = ((size_t)bb * NCHUNK + chunk) * NS;
    int pi = t & 127, sh = t >> 7;
#pragma unroll
    for (int q = 0; q < 4; q++) {
        int s = sh * 4 + q;
        f32x2 acc = h2f2v(ulH[0][s][pi]);
        f32x2 a1 = h2f2v(ulH[1][s][pi]);
        f32x2 a2 = h2f2v(ulH[2][s][pi]);
        f32x2 a3 = h2f2v(ulH[3][s][pi]);
        acc.x += a1.x + a2.x + a3.x;
        acc.y += a1.y + a2.y + a3.y;
        puH[(base + s) * 128 + pi] = pkh(acc.x, acc.y);
    }
    if (t < NS)
        pda[base + t] = dl[0][t] + dl[1][t] + dl[2][t] + dl[3][t];
}

// ================= per-iter: fin + GRU fused (grid 32x8, 512 thr) ============
__global__ void __launch_bounds__(512)
k_fingru(const unsigned* __restrict__ puH, const float* __restrict__ pda,
         const float* __restrict__ slots,
         const unsigned* __restrict__ w2cH, const unsigned* __restrict__ whhH,
         const float* __restrict__ b2g, const float* __restrict__ bhh,
         float* __restrict__ news) {
    int bb = blockIdx.x, ot = blockIdx.y, t = threadIdx.x;
    __shared__ unsigned AlH[NS][128], SlH[NS][128];
    __shared__ float pp[7][64][24];
    __shared__ float den[NS];
    // den[s] = sum_c pda (64 chunks: 8 lane-groups x 8 each)
    if (t < 64) {
        int s = t & 7, cg = t >> 3;
        float a = 0.f;
#pragma unroll
        for (int c = 0; c < 8; c++)
            a += pda[((size_t)bb * NCHUNK + cg * 8 + c) * NS + s];
        a += DPPF(a, 0x128);
        a = addx16(a);
        a = addx32(a);
        if (t < 8) den[s] = a;
    }
    // SlH pack
#pragma unroll
    for (int k = 0; k < 2; k++) {
        int idx = t + k * 512;
        int rr = idx >> 7, pi2 = idx & 127;
        float2 sv = *(const float2*)&slots[(size_t)bb * 2048 + rr * 256 + 2 * pi2];
        SlH[rr][pi2] = pkh(sv.x, sv.y);
    }
    // raw pu chunk-sums (2 packed indices per thread)
    f32x2 raw[2];
#pragma unroll
    for (int k = 0; k < 2; k++) {
        int idx = t + k * 512;
        int s = idx >> 7, pi2 = idx & 127;
        f32x2 a = {0.f, 0.f};
        const unsigned* src = puH + ((size_t)bb * NCHUNK * NS + s) * 128 + pi2;
#pragma unroll 8
        for (int c = 0; c < NCHUNK; c++) {
            f32x2 v = h2f2v(src[(size_t)c * NS * 128]);
            a.x += v.x; a.y += v.y;
        }
        raw[k] = a;
    }
    __syncthreads();
#pragma unroll
    for (int k = 0; k < 2; k++) {
        int idx = t + k * 512;
        int s = idx >> 7, pi2 = idx & 127;
        float inv = __fdividef(1.f, den[s]);
        AlH[s][pi2] = pkh(raw[k].x * inv, raw[k].y * inv);
    }
    __syncthreads();
    // GRU (4-oc uint4 + fdot2, Ksplit8)
    int q = t & 7, r = (t >> 3) & 7, kp = t >> 6;
    int oc0 = ot * 32 + q * 4;
    float ir[4] = {}, iz[4] = {}, in_[4] = {}, hr[4] = {}, hz[4] = {}, hn[4] = {};
    int p0 = kp * 16;
#pragma unroll 4
    for (int i = 0; i < 16; i++) {
        int ep = p0 + i;
        uint4 w0 = *(const uint4*)&w2cH[(size_t)ep * 768 + oc0];
        uint4 w1 = *(const uint4*)&w2cH[(size_t)ep * 768 + oc0 + 256];
        uint4 w2 = *(const uint4*)&w2cH[(size_t)ep * 768 + oc0 + 512];
        uint4 u0 = *(const uint4*)&whhH[(size_t)ep * 768 + oc0];
        uint4 u1 = *(const uint4*)&whhH[(size_t)ep * 768 + oc0 + 256];
        uint4 u2 = *(const uint4*)&whhH[(size_t)ep * 768 + oc0 + 512];
        unsigned ah = AlH[r][ep], hh = SlH[r][ep];
        const unsigned* w0u = (const unsigned*)&w0;
        const unsigned* w1u = (const unsigned*)&w1;
        const unsigned* w2u = (const unsigned*)&w2;
        const unsigned* u0u = (const unsigned*)&u0;
        const unsigned* u1u = (const unsigned*)&u1;
        const unsigned* u2u = (const unsigned*)&u2;
#pragma unroll
        for (int j = 0; j < 4; j++) {
            ir[j]  = fdot2u(w0u[j], ah, ir[j]);
            iz[j]  = fdot2u(w1u[j], ah, iz[j]);
            in_[j] = fdot2u(w2u[j], ah, in_[j]);
            hr[j]  = fdot2u(u0u[j], hh, hr[j]);
            hz[j]  = fdot2u(u1u[j], hh, hz[j]);
            hn[j]  = fdot2u(u2u[j], hh, hn[j]);
        }
    }
    int slot = (r << 3) | q;
    if (kp) {
        float* d = &pp[kp - 1][slot][0];
#pragma unroll
        for (int j = 0; j < 4; j++) {
            d[j] = ir[j]; d[4 + j] = iz[j]; d[8 + j] = in_[j];
            d[12 + j] = hr[j]; d[16 + j] = hz[j]; d[20 + j] = hn[j];
        }
    }
    __syncthreads();
    if (!kp) {
#pragma unroll
        for (int k = 0; k < 7; k++) {
            const float* s_ = &pp[k][slot][0];
#pragma unroll
            for (int j = 0; j < 4; j++) {
                ir[j] += s_[j]; iz[j] += s_[4 + j]; in_[j] += s_[8 + j];
                hr[j] += s_[12 + j]; hz[j] += s_[16 + j]; hn[j] += s_[20 + j];
            }
        }
        float4 hv = *(const float4*)&slots[((size_t)bb * NS + r) * DIM + oc0];
        float hvv[4] = {hv.x, hv.y, hv.z, hv.w};
        float out[4];
#pragma unroll
        for (int j = 0; j < 4; j++) {
            int oc = oc0 + j;
            float gir = ir[j] + b2g[oc], giz = iz[j] + b2g[oc + 256], gin = in_[j] + b2g[oc + 512];
            float ghr = hr[j] + bhh[oc], ghz = hz[j] + bhh[oc + 256], ghn = hn[j] + bhh[oc + 512];
            float rg = 1.f / (1.f + __expf(-(gir + ghr)));
            float zg = 1.f / (1.f + __expf(-(giz + ghz)));
            float ng = tanhf(fmaf(rg, ghn, gin));
            out[j] = fmaf(zg, hvv[j] - ng, ng);
        }
        *(float4*)&news[((size_t)bb * NS + r) * DIM + oc0] = float4{out[0], out[1], out[2], out[3]};
    }
}

// ================= per-iter: LN(news) + FF1 -> packed h1 =====================
__global__ void __launch_bounds__(512)
k_ff1(const float* __restrict__ news, const unsigned* __restrict__ f1H,
      const float* __restrict__ f1bp, unsigned* __restrict__ h1H) {
    int bb = blockIdx.x, ht = blockIdx.y, t = threadIdx.x;
    int wave = t >> 6, lane = t & 63;
    __shared__ unsigned ZH[NS][128];
    __shared__ float pp[3][128][4];
    {
        float4 xv = *(const float4*)&news[((size_t)bb * NS + wave) * DIM + lane * 4];
        float S, Q;
        tree2(xv.x + xv.y + xv.z + xv.w,
              xv.x * xv.x + xv.y * xv.y + xv.z * xv.z + xv.w * xv.w, lane, S, Q);
        float m = S * (1.f / DIM);
        float rstd = rsqrtf(Q * (1.f / DIM) - m * m + LN_EPS);
        ZH[wave][lane * 2]     = pkh((xv.x - m) * rstd, (xv.y - m) * rstd);
        ZH[wave][lane * 2 + 1] = pkh((xv.z - m) * rstd, (xv.w - m) * rstd);
    }
    __syncthreads();
    int cq = t & 15, r = (t >> 4) & 7, kp = t >> 7;
    int c0 = ht * 64 + cq * 4;
    float acc[4] = {};
    int p0 = kp * 32;
#pragma unroll 4
    for (int i = 0; i < 32; i++) {
        int ep = p0 + i;
        uint4 wv4 = *(const uint4*)&f1H[(size_t)ep * HID + c0];
        unsigned zh = ZH[r][ep];
        const unsigned* wu = (const unsigned*)&wv4;
#pragma unroll
        for (int j = 0; j < 4; j++) acc[j] = fdot2u(wu[j], zh, acc[j]);
    }
    int slot = (r << 4) | cq;
    if (kp) {
        float* d = &pp[kp - 1][slot][0];
#pragma unroll
        for (int j = 0; j < 4; j++) d[j] = acc[j];
    }
    __syncthreads();
    if (!kp) {
#pragma unroll
        for (int k = 0; k < 3; k++) {
            const float* s_ = &pp[k][slot][0];
#pragma unroll
            for (int j = 0; j < 4; j++) acc[j] += s_[j];
        }
        float h0 = fmaxf(acc[0] + f1bp[c0 + 0], 0.f);
        float h1v = fmaxf(acc[1] + f1bp[c0 + 1], 0.f);
        float h2 = fmaxf(acc[2] + f1bp[c0 + 2], 0.f);
        float h3 = fmaxf(acc[3] + f1bp[c0 + 3], 0.f);
        uint2 st;
        st.x = pkh(h0, h1v);
        st.y = pkh(h2, h3);
        *(uint2*)&h1H[((size_t)bb * NS + r) * 256 + c0 / 2] = st;
    }
}

// ================= per-iter: FF2 + residual (4-oc uint4 + fdot2, Ksplit8) ====
__global__ void __launch_bounds__(512)
k_ff2(const unsigned* __restrict__ h1H, const unsigned* __restrict__ f2H,
      const float* __restrict__ f2b, const float* __restrict__ news,
      float* __restrict__ slots) {
    int bb = blockIdx.x, ot = blockIdx.y, t = threadIdx.x;
    __shared__ unsigned HH[NS][256];
    __shared__ float pp[7][64][4];
    for (int idx = t; idx < 512; idx += 512)
        ((uint4*)HH)[idx] = ((const uint4*)(h1H + (size_t)bb * NS * 256))[idx];
    __syncthreads();
    int q = t & 7, r = (t >> 3) & 7, kp = t >> 6;
    int oc0 = ot * 32 + q * 4;
    float acc[4] = {};
    int p0 = kp * 32;
#pragma unroll 4
    for (int i = 0; i < 32; i++) {
        int ep = p0 + i;
        uint4 wv4 = *(const uint4*)&f2H[(size_t)ep * 256 + oc0];
        unsigned hh = HH[r][ep];
        const unsigned* wu = (const unsigned*)&wv4;
#pragma unroll
        for (int j = 0; j < 4; j++) acc[j] = fdot2u(wu[j], hh, acc[j]);
    }
    int slot = (r << 3) | q;
    if (kp) {
        float* d = &pp[kp - 1][slot][0];
#pragma unroll
        for (int j = 0; j < 4; j++) d[j] = acc[j];
    }
    __syncthreads();
    if (!kp) {
#pragma unroll
        for (int k = 0; k < 7; k++) {
            const float* s_ = &pp[k][slot][0];
#pragma unroll
            for (int j = 0; j < 4; j++) acc[j] += s_[j];
        }
        float4 nv = *(const float4*)&news[((size_t)bb * NS + r) * DIM + oc0];
        float4 bv4 = *(const float4*)&f2b[oc0];
        float4 out = {nv.x + acc[0] + bv4.x, nv.y + acc[1] + bv4.y,
                      nv.z + acc[2] + bv4.z, nv.w + acc[3] + bv4.w};
        *(float4*)&slots[((size_t)bb * NS + r) * DIM + oc0] = out;
    }
}

// ================= per-iter: LN(slots) + qk + c2 (4-oc uint4, Ksplit8) =======
__global__ void __launch_bounds__(512)
k_qk2(const float* __restrict__ slots, const unsigned* __restrict__ MppH,
      const float* __restrict__ biasp, const float* __restrict__ u2p,
      float* __restrict__ qkw, float* __restrict__ c2b) {
    int bb = blockIdx.x, ot = blockIdx.y, t = threadIdx.x;
    int wave = t >> 6, lane = t & 63;
    __shared__ unsigned ZH[NS][128];
    __shared__ float pp[7][64][4];
    {
        float4 xv = *(const float4*)&slots[((size_t)bb * NS + wave) * DIM + lane * 4];
        float S, Q;
        tree2(xv.x + xv.y + xv.z + xv.w,
              xv.x * xv.x + xv.y * xv.y + xv.z * xv.z + xv.w * xv.w, lane, S, Q);
        float m = S * (1.f / DIM);
        float rstd = rsqrtf(Q * (1.f / DIM) - m * m + LN_EPS);
        ZH[wave][lane * 2]     = pkh((xv.x - m) * rstd, (xv.y - m) * rstd);
        ZH[wave][lane * 2 + 1] = pkh((xv.z - m) * rstd, (xv.w - m) * rstd);
    }
    __syncthreads();
    int q = t & 7, r = (t >> 3) & 7, kp = t >> 6;
    int oc0 = ot * 32 + q * 4;
    float acc[4] = {};
    int p0 = kp * 16;
#pragma unroll 4
    for (int i = 0; i < 16; i++) {
        int ep = p0 + i;
        uint4 wv4 = *(const uint4*)&MppH[(size_t)ep * 256 + oc0];
        unsigned zh = ZH[r][ep];
        const unsigned* wu = (const unsigned*)&wv4;
#pragma unroll
        for (int j = 0; j < 4; j++) acc[j] = fdot2u(wu[j], zh, acc[j]);
    }
    int slot = (r << 3) | q;
    if (kp) {
        float* d = &pp[kp - 1][slot][0];
#pragma unroll
        for (int j = 0; j < 4; j++) d[j] = acc[j];
    }
    __syncthreads();
    if (!kp) {
#pragma unroll
        for (int k = 0; k < 7; k++) {
            const float* s_ = &pp[k][slot][0];
#pragma unroll
            for (int j = 0; j < 4; j++) acc[j] += s_[j];
        }
        float4 bv4 = *(const float4*)&biasp[oc0];
        float4 out = {acc[0] + bv4.x, acc[1] + bv4.y, acc[2] + bv4.z, acc[3] + bv4.w};
        *(float4*)&qkw[((size_t)bb * NS + r) * DIM + oc0] = out;
    }
    if (ot == 0 && t < 64) {
        int s = t >> 3, j = t & 7;
        float a = 0.f;
        for (int p = j * 16; p < j * 16 + 16; p++) {
            float2 z = h2f2(ZH[s][p]);
            a = fmaf(z.x, u2p[2 * p], fmaf(z.y, u2p[2 * p + 1], a));
        }
        a += DPPF(a, 0xB1);
        a += DPPF(a, 0x4E);
        a += DPPF(a, 0x141);
        if (j == 0) c2b[bb * NS + s] = a + biasp[256];
    }
}

extern "C" void kernel_launch(void* const* d_in, const int* in_sizes, int n_in,
                              void* d_out, int out_size, void* d_ws, size_t ws_size,
                              hipStream_t stream) {
    const float* x     = (const float*)d_in[0];
    const float* noise = (const float*)d_in[1];
    const float* mu  = (const float*)d_in[3];
    const float* sg  = (const float*)d_in[4];
    const float* wq  = (const float*)d_in[5];
    const float* bq  = (const float*)d_in[6];
    const float* wk  = (const float*)d_in[7];
    const float* bk  = (const float*)d_in[8];
    const float* wv  = (const float*)d_in[9];
    const float* bv  = (const float*)d_in[10];
    const float* wih = (const float*)d_in[11];
    const float* whh = (const float*)d_in[12];
    const float* bih = (const float*)d_in[13];
    const float* bhh = (const float*)d_in[14];
    const float* f1w = (const float*)d_in[15];
    const float* f1b = (const float*)d_in[16];
    const float* f2w = (const float*)d_in[17];
    const float* f2b = (const float*)d_in[18];
    const float* liw = (const float*)d_in[19];
    const float* lib = (const float*)d_in[20];
    const float* lsw = (const float*)d_in[21];
    const float* lsb = (const float*)d_in[22];
    const float* lfw = (const float*)d_in[23];
    const float* lfb = (const float*)d_in[24];
    float* slots = (float*)d_out;

    __half* xh = (__half*)d_ws;                         // 64 MB
    float* p = (float*)(xh + (size_t)NB * NTOK * DIM);
    unsigned* MppH = (unsigned*)p; p += 128 * 256;
    unsigned* w2cH = (unsigned*)p; p += 128 * 768;
    unsigned* whhH = (unsigned*)p; p += 128 * 768;
    unsigned* f1H  = (unsigned*)p; p += 128 * 512;
    unsigned* f2H  = (unsigned*)p; p += 256 * 256;
    unsigned* h1H  = (unsigned*)p; p += NROWS * 256;
    unsigned* puH  = (unsigned*)p; p += (size_t)NB * NCHUNK * NS * 128;
    float* u2p   = p; p += 256;
    float* biasp = p; p += 257;
    float* f1bp  = p; p += 512;
    float* b2g   = p; p += 768;
    float* qkw   = p; p += NROWS * 256;
    float* c2b   = p; p += NROWS;
    float* pda   = p; p += NB * NCHUNK * NS;
    float* news  = p; p += NROWS * 256;

    k_pre<<<WP_BLKS, 256, 0, stream>>>(
        wq, wk, bk, bq, lsb, lsw, MppH, u2p, biasp,
        wv, wih, w2cH,
        f1w, f1b, lfb, f1bp,
        bih, bv, b2g,
        whh, f2w, lfw, whhH, f1H, f2H);
    k_iq<<<NB, 512, 0, stream>>>(noise, mu, sg, slots, MppH, biasp, u2p, qkw, c2b);

    for (int it = 0; it < 3; it++) {
        if (it == 0)
            k_attnT<true><<<dim3(NB, NCHUNK), 256, 0, stream>>>(
                x, liw, lib, xh, qkw, c2b, puH, pda);
        else
            k_attnT<false><<<dim3(NB, NCHUNK), 256, 0, stream>>>(
                x, liw, lib, xh, qkw, c2b, puH, pda);
        k_fingru<<<dim3(NB, NS), 512, 0, stream>>>(puH, pda, slots, w2cH, whhH,
                                                   b2g, bhh, news);
        k_ff1<<<dim3(NB, NS), 512, 0, stream>>>(news, f1H, f1bp, h1H);
        k_ff2<<<dim3(NB, NS), 512, 0, stream>>>(h1H, f2H, f2b, news, slots);
        if (it < 2)
            k_qk2<<<dim3(NB, NS), 512, 0, stream>>>(slots, MppH, biasp, u2p, qkw, c2b);
    }
}

// Round 16
// 236.612 us; speedup vs baseline: 1.5149x; 1.5149x over previous
//
#include <hip/hip_runtime.h>
#include <hip/hip_fp16.h>
#include <math.h>

#define NB 32
#define NTOK 4096
#define DIM 256
#define NS 8
#define HID 512
#define NCHUNK 64
#define LN_EPS 1e-5f
#define ATT_EPS 1e-8f
#define SCALE 0.0625f
#define NROWS (NB * NS)   // 256

// ---- cross-lane primitives (VALU-pipe: DPP / permlane) ---------------------
#define DPPF(x, ctrl) __int_as_float(__builtin_amdgcn_update_dpp(0, __float_as_int(x), (ctrl), 0xF, 0xF, true))
// 0xB1 quad_perm xor1, 0x4E quad_perm xor2, 0x141 row_half_mirror (xor7),
// 0x124 row_ror:4, 0x128 row_ror:8

__device__ __forceinline__ float addx16(float c) {
#if __has_builtin(__builtin_amdgcn_permlane16_swap)
    auto r = __builtin_amdgcn_permlane16_swap(__float_as_uint(c), __float_as_uint(c), false, false);
    return __uint_as_float(r[0]) + __uint_as_float(r[1]);
#else
    return c + __shfl_xor(c, 16);
#endif
}
__device__ __forceinline__ float addx32(float c) {
#if __has_builtin(__builtin_amdgcn_permlane32_swap)
    auto r = __builtin_amdgcn_permlane32_swap(__float_as_uint(c), __float_as_uint(c), false, false);
    return __uint_as_float(r[0]) + __uint_as_float(r[1]);
#else
    return c + __shfl_xor(c, 32);
#endif
}

// sum + sumsq over 64 lanes, both results in every lane.
__device__ __forceinline__ void tree2(float v0, float v1, int lane, float& S, float& Q) {
    bool hi = lane & 1;
    float send = hi ? v0 : v1;
    float recv = DPPF(send, 0xB1);
    float a = (hi ? v1 : v0) + recv;
    a += DPPF(a, 0x4E);
    a += DPPF(a, 0x124);
    a += DPPF(a, 0x128);
    a = addx16(a);
    a = addx32(a);
    float other = DPPF(a, 0xB1);
    S = hi ? other : a;
    Q = hi ? a : other;
}

// sum + sumsq over each 32-lane half-wave, both results in every lane of half.
__device__ __forceinline__ void tree2h(float v0, float v1, int lane, float& S, float& Q) {
    bool hi = lane & 1;
    float send = hi ? v0 : v1;
    float recv = DPPF(send, 0xB1);
    float a = (hi ? v1 : v0) + recv;
    a += DPPF(a, 0x4E);
    a += DPPF(a, 0x124);
    a += DPPF(a, 0x128);
    a = addx16(a);
    float other = DPPF(a, 0xB1);
    S = hi ? other : a;
    Q = hi ? a : other;
}

// 8 independent sums over a 32-lane half-wave; lane ends with full half-wave
// sum of slot sig(lane) = (l0<<2)|(l1<<1)|(l0^l1^l2).
__device__ __forceinline__ float tree8h(const float v[8], int lane) {
    bool b0 = lane & 1;
    bool b1 = lane & 2;
    bool bp = ((lane ^ (lane >> 1) ^ (lane >> 2)) & 1);
    float a[4];
#pragma unroll
    for (int j = 0; j < 4; j++) {
        float send = b0 ? v[j] : v[4 + j];
        float recv = DPPF(send, 0xB1);
        a[j] = (b0 ? v[4 + j] : v[j]) + recv;
    }
    float b[2];
#pragma unroll
    for (int j = 0; j < 2; j++) {
        float send = b1 ? a[j] : a[2 + j];
        float recv = DPPF(send, 0x4E);
        b[j] = (b1 ? a[2 + j] : a[j]) + recv;
    }
    float send = bp ? b[0] : b[1];
    float recv = DPPF(send, 0x141);
    float c = (bp ? b[1] : b[0]) + recv;
    c += DPPF(c, 0x128);
    c = addx16(c);
    return c;
}

typedef _Float16 h2v __attribute__((ext_vector_type(2)));
typedef float f32x2 __attribute__((ext_vector_type(2)));
__device__ __forceinline__ float fdot2u(unsigned a, unsigned b, float c) {
#if __has_builtin(__builtin_amdgcn_fdot2)
    return __builtin_amdgcn_fdot2(__builtin_bit_cast(h2v, a), __builtin_bit_cast(h2v, b), c, false);
#else
    __half2 ha = __builtin_bit_cast(__half2, a), hb = __builtin_bit_cast(__half2, b);
    return c + __low2float(ha) * __low2float(hb) + __high2float(ha) * __high2float(hb);
#endif
}
__device__ __forceinline__ unsigned pkh(float a, float b) {
    return __builtin_bit_cast(unsigned, __floats2half2_rn(a, b));
}
__device__ __forceinline__ float2 h2f2(unsigned u) {
    __half2 h = __builtin_bit_cast(__half2, u);
    return float2{__low2float(h), __high2float(h)};
}
__device__ __forceinline__ f32x2 h2f2v(unsigned u) {
    __half2 h = __builtin_bit_cast(__half2, u);
    return f32x2{__low2float(h), __high2float(h)};
}
// packed 2x f32 FMA: acc = a*b + acc  (CDNA v_pk_fma_f32, full-rate)
__device__ __forceinline__ void pkfma(f32x2& acc, f32x2 a, f32x2 b) {
    asm("v_pk_fma_f32 %0, %1, %2, %0" : "+v"(acc) : "v"(a), "v"(b));
}

// ================= K1: weight prep (role-switched) ===========================
#define WP_BIAS  128
#define WP_WHH0  129
#define WP_F1H0  225
#define WP_F2H0  289
#define WP_W2C0  353
#define WP_F1B0  401
#define WP_B2G0  403
#define WP_BLKS  406

__global__ void __launch_bounds__(256)
k_pre(const float* __restrict__ wq, const float* __restrict__ wk,
      const float* __restrict__ bk, const float* __restrict__ bq,
      const float* __restrict__ lsb, const float* __restrict__ lsw,
      unsigned* __restrict__ MppH, float* __restrict__ u2p, float* __restrict__ biasp,
      const float* __restrict__ wv, const float* __restrict__ wih,
      unsigned* __restrict__ w2cH,
      const float* __restrict__ f1w, const float* __restrict__ f1b,
      const float* __restrict__ lfb, float* __restrict__ f1bp,
      const float* __restrict__ bih, const float* __restrict__ bv,
      float* __restrict__ b2g,
      const float* __restrict__ whh, const float* __restrict__ f2w,
      const float* __restrict__ lfw,
      unsigned* __restrict__ whhH, unsigned* __restrict__ f1H,
      unsigned* __restrict__ f2H) {
    int bid = blockIdx.x, t = threadIdx.x;

    if (bid < WP_BIAS) {                       // ---- MppH: e-pair (2b, 2b+1)
        int b = bid, o = t;
        float a0 = 0.f, a1 = 0.f;
        for (int d = 0; d < 256; d++) {
            float2 wqp = *(const float2*)&wq[(size_t)d * 256 + 2 * b];
            float wkv = wk[(size_t)d * 256 + o];
            a0 = fmaf(wqp.x, wkv, a0);
            a1 = fmaf(wqp.y, wkv, a1);
        }
        MppH[(size_t)b * 256 + o] = pkh(a0 * lsw[2 * b], a1 * lsw[2 * b + 1]);
        return;
    }
    if (bid == WP_BIAS) {                      // ---- biasp / u2p / k2
        int o = t;
        __shared__ float t2l[256], bkl[256], red[4];
        bkl[o] = bk[o];
        float a = bq[o];
        for (int k = 0; k < 256; k++) a = fmaf(wq[(size_t)o * 256 + k], lsb[k], a);
        t2l[o] = a;
        __syncthreads();
        float ab = 0.f, au = 0.f;
        for (int d = 0; d < 256; d++) {
            ab = fmaf(t2l[d], wk[(size_t)d * 256 + o], ab);
            au = fmaf(bkl[d], wq[(size_t)d * 256 + o], au);
        }
        biasp[o] = ab;
        u2p[o] = au * lsw[o];
        float kk = t2l[o] * bkl[o];
        kk += DPPF(kk, 0xB1);
        kk += DPPF(kk, 0x4E);
        kk += DPPF(kk, 0x124);
        kk += DPPF(kk, 0x128);
        kk = addx16(kk);
        kk = addx32(kk);
        if ((t & 63) == 0) red[t >> 6] = kk;
        __syncthreads();
        if (t == 0) biasp[256] = red[0] + red[1] + red[2] + red[3];
        return;
    }
    if (bid < WP_W2C0) {                       // ---- transpose-pack roles
        const float* in; unsigned* out; const float* scl = nullptr;
        int C, OS, r, RT;
        if (bid < WP_F1H0)      { in = whh; out = whhH; C = 256; OS = 768; r = bid - WP_WHH0; RT = 24; }
        else if (bid < WP_F2H0) { in = f1w; out = f1H;  C = 256; OS = 512; r = bid - WP_F1H0; RT = 16; scl = lfw; }
        else                    { in = f2w; out = f2H;  C = 512; OS = 256; r = bid - WP_F2H0; RT = 8; }
        int otl = r % RT, ept = r / RT;
        __shared__ float tile[32][65];
#pragma unroll
        for (int i = 0; i < 8; i++) {
            int idx = t + i * 256;
            int row = idx >> 6, col = idx & 63;
            tile[row][col] = in[(size_t)(otl * 32 + row) * C + ept * 64 + col];
        }
        __syncthreads();
#pragma unroll
        for (int i = 0; i < 4; i++) {
            int idx = t + i * 256;
            int epl = idx >> 5, ol = idx & 31;
            float v0 = tile[ol][2 * epl], v1 = tile[ol][2 * epl + 1];
            if (scl) { v0 *= scl[ept * 64 + 2 * epl]; v1 *= scl[ept * 64 + 2 * epl + 1]; }
            out[(size_t)(ept * 32 + epl) * OS + otl * 32 + ol] = pkh(v0, v1);
        }
        return;
    }
    if (bid < WP_F1B0) {                       // ---- w2cH
        int r = bid - WP_W2C0;
        int et = r & 3, ot = r >> 2;
        int ep = et * 32 + (t & 31), og = (t >> 5) * 8;
        float alo[8] = {}, ahi[8] = {};
        for (int d = 0; d < 256; d++) {
            float2 wvp = *(const float2*)&wv[(size_t)d * 256 + 2 * ep];
#pragma unroll
            for (int i = 0; i < 8; i++) {
                float wv_ih = wih[(size_t)(ot * 64 + og + i) * 256 + d];
                alo[i] = fmaf(wvp.x, wv_ih, alo[i]);
                ahi[i] = fmaf(wvp.y, wv_ih, ahi[i]);
            }
        }
#pragma unroll
        for (int i = 0; i < 8; i++)
            w2cH[(size_t)ep * 768 + ot * 64 + og + i] = pkh(alo[i], ahi[i]);
        return;
    }
    if (bid < WP_B2G0) {                       // ---- f1bp
        int h = (bid - WP_F1B0) * 256 + t;
        float a = f1b[h];
        for (int e = 0; e < 256; e++) a = fmaf(f1w[(size_t)h * 256 + e], lfb[e], a);
        f1bp[h] = a;
        return;
    }
    {                                          // ---- b2g
        int o = (bid - WP_B2G0) * 256 + t;
        float a = bih[o];
        for (int d = 0; d < 256; d++) a = fmaf(wih[(size_t)o * 256 + d], bv[d], a);
        b2g[o] = a;
    }
}

// ================= K2: slots init + first qk =================================
__global__ void __launch_bounds__(512)
k_iq(const float* __restrict__ noise, const float* __restrict__ mu,
     const float* __restrict__ sg, float* __restrict__ slots,
     const unsigned* __restrict__ MppH, const float* __restrict__ biasp,
     const float* __restrict__ u2p,
     float* __restrict__ qkw, float* __restrict__ c2b) {
    int bb = blockIdx.x, t = threadIdx.x, wave = t >> 6, lane = t & 63;
    __shared__ float S2[NS][DIM], Zl[NS][DIM];
#pragma unroll
    for (int k = 0; k < 4; k++) {
        int idx = k * 512 + t, d = idx & 255;
        float v = mu[d] + sg[d] * noise[(size_t)bb * 2048 + idx];
        S2[idx >> 8][d] = v;
        slots[(size_t)bb * 2048 + idx] = v;
    }
    __syncthreads();
    {
        float4 xv = *(const float4*)&S2[wave][lane * 4];
        float S, Q;
        tree2(xv.x + xv.y + xv.z + xv.w,
              xv.x * xv.x + xv.y * xv.y + xv.z * xv.z + xv.w * xv.w, lane, S, Q);
        float m = S * (1.f / DIM);
        float rstd = rsqrtf(Q * (1.f / DIM) - m * m + LN_EPS);
        Zl[wave][lane * 4 + 0] = (xv.x - m) * rstd;
        Zl[wave][lane * 4 + 1] = (xv.y - m) * rstd;
        Zl[wave][lane * 4 + 2] = (xv.z - m) * rstd;
        Zl[wave][lane * 4 + 3] = (xv.w - m) * rstd;
    }
    __syncthreads();
    int o = t & 255, sg2 = (t >> 8) * 4;
    float acc[4] = {};
    for (int ep = 0; ep < 128; ep++) {
        float2 wf = h2f2(MppH[(size_t)ep * 256 + o]);
#pragma unroll
        for (int i = 0; i < 4; i++) {
            float2 zp = *(const float2*)&Zl[sg2 + i][2 * ep];
            acc[i] = fmaf(zp.x, wf.x, fmaf(zp.y, wf.y, acc[i]));
        }
    }
    float bo = biasp[o];
#pragma unroll
    for (int i = 0; i < 4; i++)
        qkw[(size_t)(bb * NS + sg2 + i) * DIM + o] = acc[i] + bo;
    if (t < 64) {
        int s = t >> 3, j = t & 7;
        float a = 0.f;
        for (int e = j * 32; e < j * 32 + 32; e++) a = fmaf(Zl[s][e], u2p[e], a);
        a += DPPF(a, 0xB1);
        a += DPPF(a, 0x4E);
        a += DPPF(a, 0x141);
        if (j == 0) c2b[bb * NS + s] = a + biasp[256];
    }
}

// ================= per-iter: fused attention (64 tokens/block, deep grid) ====
// FIRST: read f32 x, inline LN -> f16 pack (also stored to xh for later iters).
// else:  read f16 xh directly.
template<bool FIRST>
__global__ void __launch_bounds__(256, 3)
k_attnT(const float* __restrict__ x, const float* __restrict__ liw,
        const float* __restrict__ lib, __half* __restrict__ xh,
        const float* __restrict__ qkw, const float* __restrict__ c2b,
        unsigned* __restrict__ puH, float* __restrict__ pda) {
    const int bb = blockIdx.x, chunk = blockIdx.y;
    const int t = threadIdx.x, wave = t >> 6, lane = t & 63;
    const int l0 = lane & 1, l1 = (lane >> 1) & 1, l2 = (lane >> 2) & 1;
    const int sig = (l0 << 2) | (l1 << 1) | (l0 ^ l1 ^ l2);
    const int e0 = (lane & 31) * 8;

    unsigned qh[NS][4];
#pragma unroll
    for (int s = 0; s < NS; s++) {
        const float4 a = *(const float4*)&qkw[(size_t)(bb * NS + s) * DIM + e0];
        const float4 b = *(const float4*)&qkw[(size_t)(bb * NS + s) * DIM + e0 + 4];
        qh[s][0] = pkh(a.x, a.y); qh[s][1] = pkh(a.z, a.w);
        qh[s][2] = pkh(b.x, b.y); qh[s][3] = pkh(b.z, b.w);
    }
    const float qbs = c2b[bb * NS + sig] * SCALE;

    f32x2 ua2[NS][4] = {};
    float da[NS] = {};

    const size_t row0 = (size_t)bb * NTOK + chunk * 64 + wave * 16 + (lane >> 5);
    const __half* xp = xh + row0 * DIM + e0;
    const float* xpf = x + row0 * DIM + e0;

    float4 wA, wB, bA, bB;
    float4 cfa, cfb;
    uint4 nxt;
    if (FIRST) {
        wA = *(const float4*)&liw[e0];
        wB = *(const float4*)&liw[e0 + 4];
        bA = *(const float4*)&lib[e0];
        bB = *(const float4*)&lib[e0 + 4];
        cfa = *(const float4*)xpf;
        cfb = *(const float4*)(xpf + 4);
    } else {
        nxt = *(const uint4*)xp;
    }

    for (int i = 0; i < 8; i++) {
        uint4 xv;
        if (FIRST) {
            float4 na, nb;
            if (i < 7) {
                na = *(const float4*)(xpf + (size_t)(i + 1) * 512);
                nb = *(const float4*)(xpf + (size_t)(i + 1) * 512 + 4);
            }
            float s1 = cfa.x + cfa.y + cfa.z + cfa.w + cfb.x + cfb.y + cfb.z + cfb.w;
            float s2 = cfa.x * cfa.x + cfa.y * cfa.y + cfa.z * cfa.z + cfa.w * cfa.w +
                       cfb.x * cfb.x + cfb.y * cfb.y + cfb.z * cfb.z + cfb.w * cfb.w;
            float S, Q;
            tree2h(s1, s2, lane, S, Q);
            float m = S * (1.f / DIM);
            float rstd = rsqrtf(Q * (1.f / DIM) - m * m + LN_EPS);
            xv.x = pkh((cfa.x - m) * rstd * wA.x + bA.x, (cfa.y - m) * rstd * wA.y + bA.y);
            xv.y = pkh((cfa.z - m) * rstd * wA.z + bA.z, (cfa.w - m) * rstd * wA.w + bA.w);
            xv.z = pkh((cfb.x - m) * rstd * wB.x + bB.x, (cfb.y - m) * rstd * wB.y + bB.y);
            xv.w = pkh((cfb.z - m) * rstd * wB.z + bB.z, (cfb.w - m) * rstd * wB.w + bB.w);
            *(uint4*)(xh + (row0 + (size_t)i * 2) * DIM + e0) = xv;
            cfa = na; cfb = nb;
        } else {
            xv = nxt;
            if (i < 7) nxt = *(const uint4*)(xp + (size_t)(i + 1) * 2 * DIM);
        }
        float dp[NS];
#pragma unroll
        for (int s = 0; s < NS; s++)
            dp[s] = fdot2u(qh[s][0], xv.x, fdot2u(qh[s][1], xv.y,
                    fdot2u(qh[s][2], xv.z, fdot2u(qh[s][3], xv.w, 0.f))));
        float ds = tree8h(dp, lane);
        float dv = fmaf(ds, SCALE, qbs);
        float mx = dv;
        mx = fmaxf(mx, DPPF(mx, 0xB1));
        mx = fmaxf(mx, DPPF(mx, 0x4E));
        mx = fmaxf(mx, DPPF(mx, 0x141));
        float e = __expf(dv - mx);
        float sm = e;
        sm += DPPF(sm, 0xB1);
        sm += DPPF(sm, 0x4E);
        sm += DPPF(sm, 0x141);
        float g0 = fmaf(e, __fdividef(1.f, sm), ATT_EPS);
        float g1 = DPPF(g0, 0x141);
        float g2 = DPPF(g0, 0x4E);
        float g3 = DPPF(g1, 0x4E);
        float g4 = DPPF(g0, 0xB1);
        float g5 = DPPF(g1, 0xB1);
        float g6 = DPPF(g2, 0xB1);
        float g7 = DPPF(g3, 0xB1);
        float gth[NS] = {g0, g1, g2, g3, g4, g5, g6, g7};
        f32x2 xd[4] = {h2f2v(xv.x), h2f2v(xv.y), h2f2v(xv.z), h2f2v(xv.w)};
#pragma unroll
        for (int j = 0; j < NS; j++) {
            float pj = gth[j];
            da[j] += pj;
            f32x2 pj2 = {pj, pj};
#pragma unroll
            for (int k = 0; k < 4; k++) pkfma(ua2[j][k], xd[k], pj2);
        }
    }
#pragma unroll
    for (int j = 0; j < NS; j++) {
        da[j] = addx32(da[j]);
#pragma unroll
        for (int k = 0; k < 4; k++) {
            ua2[j][k].x = addx32(ua2[j][k].x);
            ua2[j][k].y = addx32(ua2[j][k].y);
        }
    }
    __shared__ unsigned ulH[4][NS][128];
    __shared__ float dl[4][NS];
    const int M8[NS] = {0, 7, 3, 4, 5, 2, 6, 1};
    if (lane < 32) {
        int c0 = lane * 4;
#pragma unroll
        for (int j = 0; j < NS; j++) {
            int sj = sig ^ M8[j];
#pragma unroll
            for (int k = 0; k < 4; k++)
                ulH[wave][sj][c0 + k] = pkh(ua2[j][k].x, ua2[j][k].y);
        }
    }
    if (lane < 8) {
#pragma unroll
        for (int j = 0; j < NS; j++) dl[wave][sig ^ M8[j]] = da[j];
    }
    __syncthreads();
    size_t base = ((size_t)bb * NCHUNK + chunk) * NS;
    int pi = t & 127, sh = t >> 7;
#pragma unroll
    for (int q = 0; q < 4; q++) {
        int s = sh * 4 + q;
        f32x2 acc = h2f2v(ulH[0][s][pi]);
        f32x2 a1 = h2f2v(ulH[1][s][pi]);
        f32x2 a2 = h2f2v(ulH[2][s][pi]);
        f32x2 a3 = h2f2v(ulH[3][s][pi]);
        acc.x += a1.x + a2.x + a3.x;
        acc.y += a1.y + a2.y + a3.y;
        puH[(base + s) * 128 + pi] = pkh(acc.x, acc.y);
    }
    if (t < NS)
        pda[base + t] = dl[0][t] + dl[1][t] + dl[2][t] + dl[3][t];
}

// ================= per-iter: fin + GRU fused (grid 32x8, 512 thr) ============
__global__ void __launch_bounds__(512)
k_fingru(const unsigned* __restrict__ puH, const float* __restrict__ pda,
         const float* __restrict__ slots,
         const unsigned* __restrict__ w2cH, const unsigned* __restrict__ whhH,
         const float* __restrict__ b2g, const float* __restrict__ bhh,
         float* __restrict__ news) {
    int bb = blockIdx.x, ot = blockIdx.y, t = threadIdx.x;
    __shared__ unsigned AlH[NS][128], SlH[NS][128];
    __shared__ float pp[7][64][24];
    __shared__ float den[NS];
    // den[s] = sum_c pda (64 chunks: 8 lane-groups x 8 each)
    if (t < 64) {
        int s = t & 7, cg = t >> 3;
        float a = 0.f;
#pragma unroll
        for (int c = 0; c < 8; c++)
            a += pda[((size_t)bb * NCHUNK + cg * 8 + c) * NS + s];
        a += DPPF(a, 0x128);
        a = addx16(a);
        a = addx32(a);
        if (t < 8) den[s] = a;
    }
    // SlH pack
#pragma unroll
    for (int k = 0; k < 2; k++) {
        int idx = t + k * 512;
        int rr = idx >> 7, pi2 = idx & 127;
        float2 sv = *(const float2*)&slots[(size_t)bb * 2048 + rr * 256 + 2 * pi2];
        SlH[rr][pi2] = pkh(sv.x, sv.y);
    }
    // raw pu chunk-sums (2 packed indices per thread)
    f32x2 raw[2];
#pragma unroll
    for (int k = 0; k < 2; k++) {
        int idx = t + k * 512;
        int s = idx >> 7, pi2 = idx & 127;
        f32x2 a = {0.f, 0.f};
        const unsigned* src = puH + ((size_t)bb * NCHUNK * NS + s) * 128 + pi2;
#pragma unroll 8
        for (int c = 0; c < NCHUNK; c++) {
            f32x2 v = h2f2v(src[(size_t)c * NS * 128]);
            a.x += v.x; a.y += v.y;
        }
        raw[k] = a;
    }
    __syncthreads();
#pragma unroll
    for (int k = 0; k < 2; k++) {
        int idx = t + k * 512;
        int s = idx >> 7, pi2 = idx & 127;
        float inv = __fdividef(1.f, den[s]);
        AlH[s][pi2] = pkh(raw[k].x * inv, raw[k].y * inv);
    }
    __syncthreads();
    // GRU (4-oc uint4 + fdot2, Ksplit8)
    int q = t & 7, r = (t >> 3) & 7, kp = t >> 6;
    int oc0 = ot * 32 + q * 4;
    float ir[4] = {}, iz[4] = {}, in_[4] = {}, hr[4] = {}, hz[4] = {}, hn[4] = {};
    int p0 = kp * 16;
#pragma unroll 4
    for (int i = 0; i < 16; i++) {
        int ep = p0 + i;
        uint4 w0 = *(const uint4*)&w2cH[(size_t)ep * 768 + oc0];
        uint4 w1 = *(const uint4*)&w2cH[(size_t)ep * 768 + oc0 + 256];
        uint4 w2 = *(const uint4*)&w2cH[(size_t)ep * 768 + oc0 + 512];
        uint4 u0 = *(const uint4*)&whhH[(size_t)ep * 768 + oc0];
        uint4 u1 = *(const uint4*)&whhH[(size_t)ep * 768 + oc0 + 256];
        uint4 u2 = *(const uint4*)&whhH[(size_t)ep * 768 + oc0 + 512];
        unsigned ah = AlH[r][ep], hh = SlH[r][ep];
        const unsigned* w0u = (const unsigned*)&w0;
        const unsigned* w1u = (const unsigned*)&w1;
        const unsigned* w2u = (const unsigned*)&w2;
        const unsigned* u0u = (const unsigned*)&u0;
        const unsigned* u1u = (const unsigned*)&u1;
        const unsigned* u2u = (const unsigned*)&u2;
#pragma unroll
        for (int j = 0; j < 4; j++) {
            ir[j]  = fdot2u(w0u[j], ah, ir[j]);
            iz[j]  = fdot2u(w1u[j], ah, iz[j]);
            in_[j] = fdot2u(w2u[j], ah, in_[j]);
            hr[j]  = fdot2u(u0u[j], hh, hr[j]);
            hz[j]  = fdot2u(u1u[j], hh, hz[j]);
            hn[j]  = fdot2u(u2u[j], hh, hn[j]);
        }
    }
    int slot = (r << 3) | q;
    if (kp) {
        float* d = &pp[kp - 1][slot][0];
#pragma unroll
        for (int j = 0; j < 4; j++) {
            d[j] = ir[j]; d[4 + j] = iz[j]; d[8 + j] = in_[j];
            d[12 + j] = hr[j]; d[16 + j] = hz[j]; d[20 + j] = hn[j];
        }
    }
    __syncthreads();
    if (!kp) {
#pragma unroll
        for (int k = 0; k < 7; k++) {
            const float* s_ = &pp[k][slot][0];
#pragma unroll
            for (int j = 0; j < 4; j++) {
                ir[j] += s_[j]; iz[j] += s_[4 + j]; in_[j] += s_[8 + j];
                hr[j] += s_[12 + j]; hz[j] += s_[16 + j]; hn[j] += s_[20 + j];
            }
        }
        float4 hv = *(const float4*)&slots[((size_t)bb * NS + r) * DIM + oc0];
        float hvv[4] = {hv.x, hv.y, hv.z, hv.w};
        float out[4];
#pragma unroll
        for (int j = 0; j < 4; j++) {
            int oc = oc0 + j;
            float gir = ir[j] + b2g[oc], giz = iz[j] + b2g[oc + 256], gin = in_[j] + b2g[oc + 512];
            float ghr = hr[j] + bhh[oc], ghz = hz[j] + bhh[oc + 256], ghn = hn[j] + bhh[oc + 512];
            float rg = 1.f / (1.f + __expf(-(gir + ghr)));
            float zg = 1.f / (1.f + __expf(-(giz + ghz)));
            float ng = tanhf(fmaf(rg, ghn, gin));
            out[j] = fmaf(zg, hvv[j] - ng, ng);
        }
        *(float4*)&news[((size_t)bb * NS + r) * DIM + oc0] = float4{out[0], out[1], out[2], out[3]};
    }
}

// ================= per-iter: LN(news) + FF1 -> packed h1 =====================
__global__ void __launch_bounds__(512)
k_ff1(const float* __restrict__ news, const unsigned* __restrict__ f1H,
      const float* __restrict__ f1bp, unsigned* __restrict__ h1H) {
    int bb = blockIdx.x, ht = blockIdx.y, t = threadIdx.x;
    int wave = t >> 6, lane = t & 63;
    __shared__ unsigned ZH[NS][128];
    __shared__ float pp[3][128][4];
    {
        float4 xv = *(const float4*)&news[((size_t)bb * NS + wave) * DIM + lane * 4];
        float S, Q;
        tree2(xv.x + xv.y + xv.z + xv.w,
              xv.x * xv.x + xv.y * xv.y + xv.z * xv.z + xv.w * xv.w, lane, S, Q);
        float m = S * (1.f / DIM);
        float rstd = rsqrtf(Q * (1.f / DIM) - m * m + LN_EPS);
        ZH[wave][lane * 2]     = pkh((xv.x - m) * rstd, (xv.y - m) * rstd);
        ZH[wave][lane * 2 + 1] = pkh((xv.z - m) * rstd, (xv.w - m) * rstd);
    }
    __syncthreads();
    int cq = t & 15, r = (t >> 4) & 7, kp = t >> 7;
    int c0 = ht * 64 + cq * 4;
    float acc[4] = {};
    int p0 = kp * 32;
#pragma unroll 4
    for (int i = 0; i < 32; i++) {
        int ep = p0 + i;
        uint4 wv4 = *(const uint4*)&f1H[(size_t)ep * HID + c0];
        unsigned zh = ZH[r][ep];
        const unsigned* wu = (const unsigned*)&wv4;
#pragma unroll
        for (int j = 0; j < 4; j++) acc[j] = fdot2u(wu[j], zh, acc[j]);
    }
    int slot = (r << 4) | cq;
    if (kp) {
        float* d = &pp[kp - 1][slot][0];
#pragma unroll
        for (int j = 0; j < 4; j++) d[j] = acc[j];
    }
    __syncthreads();
    if (!kp) {
#pragma unroll
        for (int k = 0; k < 3; k++) {
            const float* s_ = &pp[k][slot][0];
#pragma unroll
            for (int j = 0; j < 4; j++) acc[j] += s_[j];
        }
        float h0 = fmaxf(acc[0] + f1bp[c0 + 0], 0.f);
        float h1v = fmaxf(acc[1] + f1bp[c0 + 1], 0.f);
        float h2 = fmaxf(acc[2] + f1bp[c0 + 2], 0.f);
        float h3 = fmaxf(acc[3] + f1bp[c0 + 3], 0.f);
        uint2 st;
        st.x = pkh(h0, h1v);
        st.y = pkh(h2, h3);
        *(uint2*)&h1H[((size_t)bb * NS + r) * 256 + c0 / 2] = st;
    }
}

// ================= per-iter: FF2 + residual (4-oc uint4 + fdot2, Ksplit8) ====
__global__ void __launch_bounds__(512)
k_ff2(const unsigned* __restrict__ h1H, const unsigned* __restrict__ f2H,
      const float* __restrict__ f2b, const float* __restrict__ news,
      float* __restrict__ slots) {
    int bb = blockIdx.x, ot = blockIdx.y, t = threadIdx.x;
    __shared__ unsigned HH[NS][256];
    __shared__ float pp[7][64][4];
    for (int idx = t; idx < 512; idx += 512)
        ((uint4*)HH)[idx] = ((const uint4*)(h1H + (size_t)bb * NS * 256))[idx];
    __syncthreads();
    int q = t & 7, r = (t >> 3) & 7, kp = t >> 6;
    int oc0 = ot * 32 + q * 4;
    float acc[4] = {};
    int p0 = kp * 32;
#pragma unroll 4
    for (int i = 0; i < 32; i++) {
        int ep = p0 + i;
        uint4 wv4 = *(const uint4*)&f2H[(size_t)ep * 256 + oc0];
        unsigned hh = HH[r][ep];
        const unsigned* wu = (const unsigned*)&wv4;
#pragma unroll
        for (int j = 0; j < 4; j++) acc[j] = fdot2u(wu[j], hh, acc[j]);
    }
    int slot = (r << 3) | q;
    if (kp) {
        float* d = &pp[kp - 1][slot][0];
#pragma unroll
        for (int j = 0; j < 4; j++) d[j] = acc[j];
    }
    __syncthreads();
    if (!kp) {
#pragma unroll
        for (int k = 0; k < 7; k++) {
            const float* s_ = &pp[k][slot][0];
#pragma unroll
            for (int j = 0; j < 4; j++) acc[j] += s_[j];
        }
        float4 nv = *(const float4*)&news[((size_t)bb * NS + r) * DIM + oc0];
        float4 bv4 = *(const float4*)&f2b[oc0];
        float4 out = {nv.x + acc[0] + bv4.x, nv.y + acc[1] + bv4.y,
                      nv.z + acc[2] + bv4.z, nv.w + acc[3] + bv4.w};
        *(float4*)&slots[((size_t)bb * NS + r) * DIM + oc0] = out;
    }
}

// ================= per-iter: LN(slots) + qk + c2 (4-oc uint4, Ksplit8) =======
__global__ void __launch_bounds__(512)
k_qk2(const float* __restrict__ slots, const unsigned* __restrict__ MppH,
      const float* __restrict__ biasp, const float* __restrict__ u2p,
      float* __restrict__ qkw, float* __restrict__ c2b) {
    int bb = blockIdx.x, ot = blockIdx.y, t = threadIdx.x;
    int wave = t >> 6, lane = t & 63;
    __shared__ unsigned ZH[NS][128];
    __shared__ float pp[7][64][4];
    {
        float4 xv = *(const float4*)&slots[((size_t)bb * NS + wave) * DIM + lane * 4];
        float S, Q;
        tree2(xv.x + xv.y + xv.z + xv.w,
              xv.x * xv.x + xv.y * xv.y + xv.z * xv.z + xv.w * xv.w, lane, S, Q);
        float m = S * (1.f / DIM);
        float rstd = rsqrtf(Q * (1.f / DIM) - m * m + LN_EPS);
        ZH[wave][lane * 2]     = pkh((xv.x - m) * rstd, (xv.y - m) * rstd);
        ZH[wave][lane * 2 + 1] = pkh((xv.z - m) * rstd, (xv.w - m) * rstd);
    }
    __syncthreads();
    int q = t & 7, r = (t >> 3) & 7, kp = t >> 6;
    int oc0 = ot * 32 + q * 4;
    float acc[4] = {};
    int p0 = kp * 16;
#pragma unroll 4
    for (int i = 0; i < 16; i++) {
        int ep = p0 + i;
        uint4 wv4 = *(const uint4*)&MppH[(size_t)ep * 256 + oc0];
        unsigned zh = ZH[r][ep];
        const unsigned* wu = (const unsigned*)&wv4;
#pragma unroll
        for (int j = 0; j < 4; j++) acc[j] = fdot2u(wu[j], zh, acc[j]);
    }
    int slot = (r << 3) | q;
    if (kp) {
        float* d = &pp[kp - 1][slot][0];
#pragma unroll
        for (int j = 0; j < 4; j++) d[j] = acc[j];
    }
    __syncthreads();
    if (!kp) {
#pragma unroll
        for (int k = 0; k < 7; k++) {
            const float* s_ = &pp[k][slot][0];
#pragma unroll
            for (int j = 0; j < 4; j++) acc[j] += s_[j];
        }
        float4 bv4 = *(const float4*)&biasp[oc0];
        float4 out = {acc[0] + bv4.x, acc[1] + bv4.y, acc[2] + bv4.z, acc[3] + bv4.w};
        *(float4*)&qkw[((size_t)bb * NS + r) * DIM + oc0] = out;
    }
    if (ot == 0 && t < 64) {
        int s = t >> 3, j = t & 7;
        float a = 0.f;
        for (int p = j * 16; p < j * 16 + 16; p++) {
            float2 z = h2f2(ZH[s][p]);
            a = fmaf(z.x, u2p[2 * p], fmaf(z.y, u2p[2 * p + 1], a));
        }
        a += DPPF(a, 0xB1);
        a += DPPF(a, 0x4E);
        a += DPPF(a, 0x141);
        if (j == 0) c2b[bb * NS + s] = a + biasp[256];
    }
}

extern "C" void kernel_launch(void* const* d_in, const int* in_sizes, int n_in,
                              void* d_out, int out_size, void* d_ws, size_t ws_size,
                              hipStream_t stream) {
    const float* x     = (const float*)d_in[0];
    const float* noise = (const float*)d_in[1];
    const float* mu  = (const float*)d_in[3];
    const float* sg  = (const float*)d_in[4];
    const float* wq  = (const float*)d_in[5];
    const float* bq  = (const float*)d_in[6];
    const float* wk  = (const float*)d_in[7];
    const float* bk  = (const float*)d_in[8];
    const float* wv  = (const float*)d_in[9];
    const float* bv  = (const float*)d_in[10];
    const float* wih = (const float*)d_in[11];
    const float* whh = (const float*)d_in[12];
    const float* bih = (const float*)d_in[13];
    const float* bhh = (const float*)d_in[14];
    const float* f1w = (const float*)d_in[15];
    const float* f1b = (const float*)d_in[16];
    const float* f2w = (const float*)d_in[17];
    const float* f2b = (const float*)d_in[18];
    const float* liw = (const float*)d_in[19];
    const float* lib = (const float*)d_in[20];
    const float* lsw = (const float*)d_in[21];
    const float* lsb = (const float*)d_in[22];
    const float* lfw = (const float*)d_in[23];
    const float* lfb = (const float*)d_in[24];
    float* slots = (float*)d_out;

    __half* xh = (__half*)d_ws;                         // 64 MB
    float* p = (float*)(xh + (size_t)NB * NTOK * DIM);
    unsigned* MppH = (unsigned*)p; p += 128 * 256;
    unsigned* w2cH = (unsigned*)p; p += 128 * 768;
    unsigned* whhH = (unsigned*)p; p += 128 * 768;
    unsigned* f1H  = (unsigned*)p; p += 128 * 512;
    unsigned* f2H  = (unsigned*)p; p += 256 * 256;
    unsigned* h1H  = (unsigned*)p; p += NROWS * 256;
    unsigned* puH  = (unsigned*)p; p += (size_t)NB * NCHUNK * NS * 128;
    float* u2p   = p; p += 256;
    float* biasp = p; p += 257;
    float* f1bp  = p; p += 512;
    float* b2g   = p; p += 768;
    float* qkw   = p; p += NROWS * 256;
    float* c2b   = p; p += NROWS;
    float* pda   = p; p += NB * NCHUNK * NS;
    float* news  = p; p += NROWS * 256;

    k_pre<<<WP_BLKS, 256, 0, stream>>>(
        wq, wk, bk, bq, lsb, lsw, MppH, u2p, biasp,
        wv, wih, w2cH,
        f1w, f1b, lfb, f1bp,
        bih, bv, b2g,
        whh, f2w, lfw, whhH, f1H, f2H);
    k_iq<<<NB, 512, 0, stream>>>(noise, mu, sg, slots, MppH, biasp, u2p, qkw, c2b);

    for (int it = 0; it < 3; it++) {
        if (it == 0)
            k_attnT<true><<<dim3(NB, NCHUNK), 256, 0, stream>>>(
                x, liw, lib, xh, qkw, c2b, puH, pda);
        else
            k_attnT<false><<<dim3(NB, NCHUNK), 256, 0, stream>>>(
                x, liw, lib, xh, qkw, c2b, puH, pda);
        k_fingru<<<dim3(NB, NS), 512, 0, stream>>>(puH, pda, slots, w2cH, whhH,
                                                   b2g, bhh, news);
        k_ff1<<<dim3(NB, NS), 512, 0, stream>>>(news, f1H, f1bp, h1H);
        k_ff2<<<dim3(NB, NS), 512, 0, stream>>>(h1H, f2H, f2b, news, slots);
        if (it < 2)
            k_qk2<<<dim3(NB, NS), 512, 0, stream>>>(slots, MppH, biasp, u2p, qkw, c2b);
    }
}

// Round 17
// 213.124 us; speedup vs baseline: 1.6819x; 1.1102x over previous
//
#include <hip/hip_runtime.h>
#include <hip/hip_fp16.h>
#include <math.h>

#define NB 32
#define NTOK 4096
#define DIM 256
#define NS 8
#define HID 512
#define NCHUNK 32
#define LN_EPS 1e-5f
#define ATT_EPS 1e-8f
#define SCALE 0.0625f
#define NROWS (NB * NS)   // 256

// ---- cross-lane primitives (VALU-pipe: DPP / permlane) ---------------------
#define DPPF(x, ctrl) __int_as_float(__builtin_amdgcn_update_dpp(0, __float_as_int(x), (ctrl), 0xF, 0xF, true))
// 0xB1 quad_perm xor1, 0x4E quad_perm xor2, 0x141 row_half_mirror (xor7),
// 0x124 row_ror:4, 0x128 row_ror:8

__device__ __forceinline__ float addx16(float c) {
#if __has_builtin(__builtin_amdgcn_permlane16_swap)
    auto r = __builtin_amdgcn_permlane16_swap(__float_as_uint(c), __float_as_uint(c), false, false);
    return __uint_as_float(r[0]) + __uint_as_float(r[1]);
#else
    return c + __shfl_xor(c, 16);
#endif
}
__device__ __forceinline__ float addx32(float c) {
#if __has_builtin(__builtin_amdgcn_permlane32_swap)
    auto r = __builtin_amdgcn_permlane32_swap(__float_as_uint(c), __float_as_uint(c), false, false);
    return __uint_as_float(r[0]) + __uint_as_float(r[1]);
#else
    return c + __shfl_xor(c, 32);
#endif
}

// sum + sumsq over 64 lanes, both results in every lane.
__device__ __forceinline__ void tree2(float v0, float v1, int lane, float& S, float& Q) {
    bool hi = lane & 1;
    float send = hi ? v0 : v1;
    float recv = DPPF(send, 0xB1);
    float a = (hi ? v1 : v0) + recv;
    a += DPPF(a, 0x4E);
    a += DPPF(a, 0x124);
    a += DPPF(a, 0x128);
    a = addx16(a);
    a = addx32(a);
    float other = DPPF(a, 0xB1);
    S = hi ? other : a;
    Q = hi ? a : other;
}

// sum + sumsq over each 32-lane half-wave, both results in every lane of half.
__device__ __forceinline__ void tree2h(float v0, float v1, int lane, float& S, float& Q) {
    bool hi = lane & 1;
    float send = hi ? v0 : v1;
    float recv = DPPF(send, 0xB1);
    float a = (hi ? v1 : v0) + recv;
    a += DPPF(a, 0x4E);
    a += DPPF(a, 0x124);
    a += DPPF(a, 0x128);
    a = addx16(a);
    float other = DPPF(a, 0xB1);
    S = hi ? other : a;
    Q = hi ? a : other;
}

// 8 independent sums over a 32-lane half-wave; lane ends with full half-wave
// sum of slot sig(lane) = (l0<<2)|(l1<<1)|(l0^l1^l2).
__device__ __forceinline__ float tree8h(const float v[8], int lane) {
    bool b0 = lane & 1;
    bool b1 = lane & 2;
    bool bp = ((lane ^ (lane >> 1) ^ (lane >> 2)) & 1);
    float a[4];
#pragma unroll
    for (int j = 0; j < 4; j++) {
        float send = b0 ? v[j] : v[4 + j];
        float recv = DPPF(send, 0xB1);
        a[j] = (b0 ? v[4 + j] : v[j]) + recv;
    }
    float b[2];
#pragma unroll
    for (int j = 0; j < 2; j++) {
        float send = b1 ? a[j] : a[2 + j];
        float recv = DPPF(send, 0x4E);
        b[j] = (b1 ? a[2 + j] : a[j]) + recv;
    }
    float send = bp ? b[0] : b[1];
    float recv = DPPF(send, 0x141);
    float c = (bp ? b[1] : b[0]) + recv;
    c += DPPF(c, 0x128);
    c = addx16(c);
    return c;
}

typedef _Float16 h2v __attribute__((ext_vector_type(2)));
typedef float f32x2 __attribute__((ext_vector_type(2)));
__device__ __forceinline__ float fdot2u(unsigned a, unsigned b, float c) {
#if __has_builtin(__builtin_amdgcn_fdot2)
    return __builtin_amdgcn_fdot2(__builtin_bit_cast(h2v, a), __builtin_bit_cast(h2v, b), c, false);
#else
    __half2 ha = __builtin_bit_cast(__half2, a), hb = __builtin_bit_cast(__half2, b);
    return c + __low2float(ha) * __low2float(hb) + __high2float(ha) * __high2float(hb);
#endif
}
__device__ __forceinline__ unsigned pkh(float a, float b) {
    return __builtin_bit_cast(unsigned, __floats2half2_rn(a, b));
}
__device__ __forceinline__ float2 h2f2(unsigned u) {
    __half2 h = __builtin_bit_cast(__half2, u);
    return float2{__low2float(h), __high2float(h)};
}
__device__ __forceinline__ f32x2 h2f2v(unsigned u) {
    __half2 h = __builtin_bit_cast(__half2, u);
    return f32x2{__low2float(h), __high2float(h)};
}
// packed 2x f32 FMA: acc = a*b + acc  (CDNA v_pk_fma_f32, full-rate)
__device__ __forceinline__ void pkfma(f32x2& acc, f32x2 a, f32x2 b) {
    asm("v_pk_fma_f32 %0, %1, %2, %0" : "+v"(acc) : "v"(a), "v"(b));
}

// ================= K1: weight prep (role-switched) ===========================
#define WP_BIAS  128
#define WP_WHH0  129
#define WP_F1H0  225
#define WP_F2H0  289
#define WP_W2C0  353
#define WP_F1B0  401
#define WP_B2G0  403
#define WP_BLKS  406

__global__ void __launch_bounds__(256)
k_pre(const float* __restrict__ wq, const float* __restrict__ wk,
      const float* __restrict__ bk, const float* __restrict__ bq,
      const float* __restrict__ lsb, const float* __restrict__ lsw,
      unsigned* __restrict__ MppH, float* __restrict__ u2p, float* __restrict__ biasp,
      const float* __restrict__ wv, const float* __restrict__ wih,
      unsigned* __restrict__ w2cH,
      const float* __restrict__ f1w, const float* __restrict__ f1b,
      const float* __restrict__ lfb, float* __restrict__ f1bp,
      const float* __restrict__ bih, const float* __restrict__ bv,
      float* __restrict__ b2g,
      const float* __restrict__ whh, const float* __restrict__ f2w,
      const float* __restrict__ lfw,
      unsigned* __restrict__ whhH, unsigned* __restrict__ f1H,
      unsigned* __restrict__ f2H) {
    int bid = blockIdx.x, t = threadIdx.x;

    if (bid < WP_BIAS) {                       // ---- MppH: e-pair (2b, 2b+1)
        int b = bid, o = t;
        float a0 = 0.f, a1 = 0.f;
        for (int d = 0; d < 256; d++) {
            float2 wqp = *(const float2*)&wq[(size_t)d * 256 + 2 * b];
            float wkv = wk[(size_t)d * 256 + o];
            a0 = fmaf(wqp.x, wkv, a0);
            a1 = fmaf(wqp.y, wkv, a1);
        }
        MppH[(size_t)b * 256 + o] = pkh(a0 * lsw[2 * b], a1 * lsw[2 * b + 1]);
        return;
    }
    if (bid == WP_BIAS) {                      // ---- biasp / u2p / k2
        int o = t;
        __shared__ float t2l[256], bkl[256], red[4];
        bkl[o] = bk[o];
        float a = bq[o];
        for (int k = 0; k < 256; k++) a = fmaf(wq[(size_t)o * 256 + k], lsb[k], a);
        t2l[o] = a;
        __syncthreads();
        float ab = 0.f, au = 0.f;
        for (int d = 0; d < 256; d++) {
            ab = fmaf(t2l[d], wk[(size_t)d * 256 + o], ab);
            au = fmaf(bkl[d], wq[(size_t)d * 256 + o], au);
        }
        biasp[o] = ab;
        u2p[o] = au * lsw[o];
        float kk = t2l[o] * bkl[o];
        kk += DPPF(kk, 0xB1);
        kk += DPPF(kk, 0x4E);
        kk += DPPF(kk, 0x124);
        kk += DPPF(kk, 0x128);
        kk = addx16(kk);
        kk = addx32(kk);
        if ((t & 63) == 0) red[t >> 6] = kk;
        __syncthreads();
        if (t == 0) biasp[256] = red[0] + red[1] + red[2] + red[3];
        return;
    }
    if (bid < WP_W2C0) {                       // ---- transpose-pack roles
        const float* in; unsigned* out; const float* scl = nullptr;
        int C, OS, r, RT;
        if (bid < WP_F1H0)      { in = whh; out = whhH; C = 256; OS = 768; r = bid - WP_WHH0; RT = 24; }
        else if (bid < WP_F2H0) { in = f1w; out = f1H;  C = 256; OS = 512; r = bid - WP_F1H0; RT = 16; scl = lfw; }
        else                    { in = f2w; out = f2H;  C = 512; OS = 256; r = bid - WP_F2H0; RT = 8; }
        int otl = r % RT, ept = r / RT;
        __shared__ float tile[32][65];
#pragma unroll
        for (int i = 0; i < 8; i++) {
            int idx = t + i * 256;
            int row = idx >> 6, col = idx & 63;
            tile[row][col] = in[(size_t)(otl * 32 + row) * C + ept * 64 + col];
        }
        __syncthreads();
#pragma unroll
        for (int i = 0; i < 4; i++) {
            int idx = t + i * 256;
            int epl = idx >> 5, ol = idx & 31;
            float v0 = tile[ol][2 * epl], v1 = tile[ol][2 * epl + 1];
            if (scl) { v0 *= scl[ept * 64 + 2 * epl]; v1 *= scl[ept * 64 + 2 * epl + 1]; }
            out[(size_t)(ept * 32 + epl) * OS + otl * 32 + ol] = pkh(v0, v1);
        }
        return;
    }
    if (bid < WP_F1B0) {                       // ---- w2cH
        int r = bid - WP_W2C0;
        int et = r & 3, ot = r >> 2;
        int ep = et * 32 + (t & 31), og = (t >> 5) * 8;
        float alo[8] = {}, ahi[8] = {};
        for (int d = 0; d < 256; d++) {
            float2 wvp = *(const float2*)&wv[(size_t)d * 256 + 2 * ep];
#pragma unroll
            for (int i = 0; i < 8; i++) {
                float wv_ih = wih[(size_t)(ot * 64 + og + i) * 256 + d];
                alo[i] = fmaf(wvp.x, wv_ih, alo[i]);
                ahi[i] = fmaf(wvp.y, wv_ih, ahi[i]);
            }
        }
#pragma unroll
        for (int i = 0; i < 8; i++)
            w2cH[(size_t)ep * 768 + ot * 64 + og + i] = pkh(alo[i], ahi[i]);
        return;
    }
    if (bid < WP_B2G0) {                       // ---- f1bp
        int h = (bid - WP_F1B0) * 256 + t;
        float a = f1b[h];
        for (int e = 0; e < 256; e++) a = fmaf(f1w[(size_t)h * 256 + e], lfb[e], a);
        f1bp[h] = a;
        return;
    }
    {                                          // ---- b2g
        int o = (bid - WP_B2G0) * 256 + t;
        float a = bih[o];
        for (int d = 0; d < 256; d++) a = fmaf(wih[(size_t)o * 256 + d], bv[d], a);
        b2g[o] = a;
    }
}

// ================= K2: slots init + first qk =================================
__global__ void __launch_bounds__(512)
k_iq(const float* __restrict__ noise, const float* __restrict__ mu,
     const float* __restrict__ sg, float* __restrict__ slots,
     const unsigned* __restrict__ MppH, const float* __restrict__ biasp,
     const float* __restrict__ u2p,
     float* __restrict__ qkw, float* __restrict__ c2b) {
    int bb = blockIdx.x, t = threadIdx.x, wave = t >> 6, lane = t & 63;
    __shared__ float S2[NS][DIM], Zl[NS][DIM];
#pragma unroll
    for (int k = 0; k < 4; k++) {
        int idx = k * 512 + t, d = idx & 255;
        float v = mu[d] + sg[d] * noise[(size_t)bb * 2048 + idx];
        S2[idx >> 8][d] = v;
        slots[(size_t)bb * 2048 + idx] = v;
    }
    __syncthreads();
    {
        float4 xv = *(const float4*)&S2[wave][lane * 4];
        float S, Q;
        tree2(xv.x + xv.y + xv.z + xv.w,
              xv.x * xv.x + xv.y * xv.y + xv.z * xv.z + xv.w * xv.w, lane, S, Q);
        float m = S * (1.f / DIM);
        float rstd = rsqrtf(Q * (1.f / DIM) - m * m + LN_EPS);
        Zl[wave][lane * 4 + 0] = (xv.x - m) * rstd;
        Zl[wave][lane * 4 + 1] = (xv.y - m) * rstd;
        Zl[wave][lane * 4 + 2] = (xv.z - m) * rstd;
        Zl[wave][lane * 4 + 3] = (xv.w - m) * rstd;
    }
    __syncthreads();
    int o = t & 255, sg2 = (t >> 8) * 4;
    float acc[4] = {};
    for (int ep = 0; ep < 128; ep++) {
        float2 wf = h2f2(MppH[(size_t)ep * 256 + o]);
#pragma unroll
        for (int i = 0; i < 4; i++) {
            float2 zp = *(const float2*)&Zl[sg2 + i][2 * ep];
            acc[i] = fmaf(zp.x, wf.x, fmaf(zp.y, wf.y, acc[i]));
        }
    }
    float bo = biasp[o];
#pragma unroll
    for (int i = 0; i < 4; i++)
        qkw[(size_t)(bb * NS + sg2 + i) * DIM + o] = acc[i] + bo;
    if (t < 64) {
        int s = t >> 3, j = t & 7;
        float a = 0.f;
        for (int e = j * 32; e < j * 32 + 32; e++) a = fmaf(Zl[s][e], u2p[e], a);
        a += DPPF(a, 0xB1);
        a += DPPF(a, 0x4E);
        a += DPPF(a, 0x141);
        if (j == 0) c2b[bb * NS + s] = a + biasp[256];
    }
}

// ================= per-iter: fused attention (transposed grid) ===============
// FIRST: read f32 x, inline LN -> f16 pack (also stored to xh for later iters).
// else:  read f16 xh directly.
template<bool FIRST>
__global__ void __launch_bounds__(256, 3)
k_attnT(const float* __restrict__ x, const float* __restrict__ liw,
        const float* __restrict__ lib, __half* __restrict__ xh,
        const float* __restrict__ qkw, const float* __restrict__ c2b,
        unsigned* __restrict__ puH, float* __restrict__ pda) {
    const int bb = blockIdx.y, chunk = blockIdx.x;
    const int t = threadIdx.x, wave = t >> 6, lane = t & 63;
    const int l0 = lane & 1, l1 = (lane >> 1) & 1, l2 = (lane >> 2) & 1;
    const int sig = (l0 << 2) | (l1 << 1) | (l0 ^ l1 ^ l2);
    const int e0 = (lane & 31) * 8;

    unsigned qh[NS][4];
#pragma unroll
    for (int s = 0; s < NS; s++) {
        const float4 a = *(const float4*)&qkw[(size_t)(bb * NS + s) * DIM + e0];
        const float4 b = *(const float4*)&qkw[(size_t)(bb * NS + s) * DIM + e0 + 4];
        qh[s][0] = pkh(a.x, a.y); qh[s][1] = pkh(a.z, a.w);
        qh[s][2] = pkh(b.x, b.y); qh[s][3] = pkh(b.z, b.w);
    }
    const float qbs = c2b[bb * NS + sig] * SCALE;

    f32x2 ua2[NS][4] = {};
    float da[NS] = {};

    const size_t row0 = (size_t)bb * NTOK + chunk * 128 + wave * 32 + (lane >> 5);
    const __half* xp = xh + row0 * DIM + e0;
    const float* xpf = x + row0 * DIM + e0;

    float4 wA, wB, bA, bB;
    float4 cfa, cfb;
    uint4 nxt;
    if (FIRST) {
        wA = *(const float4*)&liw[e0];
        wB = *(const float4*)&liw[e0 + 4];
        bA = *(const float4*)&lib[e0];
        bB = *(const float4*)&lib[e0 + 4];
        cfa = *(const float4*)xpf;
        cfb = *(const float4*)(xpf + 4);
    } else {
        nxt = *(const uint4*)xp;
    }

    for (int i = 0; i < 16; i++) {
        uint4 xv;
        if (FIRST) {
            float4 na, nb;
            if (i < 15) {
                na = *(const float4*)(xpf + (size_t)(i + 1) * 512);
                nb = *(const float4*)(xpf + (size_t)(i + 1) * 512 + 4);
            }
            float s1 = cfa.x + cfa.y + cfa.z + cfa.w + cfb.x + cfb.y + cfb.z + cfb.w;
            float s2 = cfa.x * cfa.x + cfa.y * cfa.y + cfa.z * cfa.z + cfa.w * cfa.w +
                       cfb.x * cfb.x + cfb.y * cfb.y + cfb.z * cfb.z + cfb.w * cfb.w;
            float S, Q;
            tree2h(s1, s2, lane, S, Q);
            float m = S * (1.f / DIM);
            float rstd = rsqrtf(Q * (1.f / DIM) - m * m + LN_EPS);
            xv.x = pkh((cfa.x - m) * rstd * wA.x + bA.x, (cfa.y - m) * rstd * wA.y + bA.y);
            xv.y = pkh((cfa.z - m) * rstd * wA.z + bA.z, (cfa.w - m) * rstd * wA.w + bA.w);
            xv.z = pkh((cfb.x - m) * rstd * wB.x + bB.x, (cfb.y - m) * rstd * wB.y + bB.y);
            xv.w = pkh((cfb.z - m) * rstd * wB.z + bB.z, (cfb.w - m) * rstd * wB.w + bB.w);
            *(uint4*)(xh + (row0 + (size_t)i * 2) * DIM + e0) = xv;
            cfa = na; cfb = nb;
        } else {
            xv = nxt;
            if (i < 15) nxt = *(const uint4*)(xp + (size_t)(i + 1) * 2 * DIM);
        }
        float dp[NS];
#pragma unroll
        for (int s = 0; s < NS; s++)
            dp[s] = fdot2u(qh[s][0], xv.x, fdot2u(qh[s][1], xv.y,
                    fdot2u(qh[s][2], xv.z, fdot2u(qh[s][3], xv.w, 0.f))));
        float ds = tree8h(dp, lane);
        float dv = fmaf(ds, SCALE, qbs);
        float mx = dv;
        mx = fmaxf(mx, DPPF(mx, 0xB1));
        mx = fmaxf(mx, DPPF(mx, 0x4E));
        mx = fmaxf(mx, DPPF(mx, 0x141));
        float e = __expf(dv - mx);
        float sm = e;
        sm += DPPF(sm, 0xB1);
        sm += DPPF(sm, 0x4E);
        sm += DPPF(sm, 0x141);
        float g0 = fmaf(e, __fdividef(1.f, sm), ATT_EPS);
        float g1 = DPPF(g0, 0x141);
        float g2 = DPPF(g0, 0x4E);
        float g3 = DPPF(g1, 0x4E);
        float g4 = DPPF(g0, 0xB1);
        float g5 = DPPF(g1, 0xB1);
        float g6 = DPPF(g2, 0xB1);
        float g7 = DPPF(g3, 0xB1);
        float gth[NS] = {g0, g1, g2, g3, g4, g5, g6, g7};
        f32x2 xd[4] = {h2f2v(xv.x), h2f2v(xv.y), h2f2v(xv.z), h2f2v(xv.w)};
#pragma unroll
        for (int j = 0; j < NS; j++) {
            float pj = gth[j];
            da[j] += pj;
            f32x2 pj2 = {pj, pj};
#pragma unroll
            for (int k = 0; k < 4; k++) pkfma(ua2[j][k], xd[k], pj2);
        }
    }
#pragma unroll
    for (int j = 0; j < NS; j++) {
        da[j] = addx32(da[j]);
#pragma unroll
        for (int k = 0; k < 4; k++) {
            ua2[j][k].x = addx32(ua2[j][k].x);
            ua2[j][k].y = addx32(ua2[j][k].y);
        }
    }
    __shared__ unsigned ulH[4][NS][128];
    __shared__ float dl[4][NS];
    const int M8[NS] = {0, 7, 3, 4, 5, 2, 6, 1};
    if (lane < 32) {
        int c0 = lane * 4;
#pragma unroll
        for (int j = 0; j < NS; j++) {
            int sj = sig ^ M8[j];
#pragma unroll
            for (int k = 0; k < 4; k++)
                ulH[wave][sj][c0 + k] = pkh(ua2[j][k].x, ua2[j][k].y);
        }
    }
    if (lane < 8) {
#pragma unroll
        for (int j = 0; j < NS; j++) dl[wave][sig ^ M8[j]] = da[j];
    }
    __syncthreads();
    size_t base = ((size_t)bb * NCHUNK + chunk) * NS;
    int pi = t & 127, sh = t >> 7;
#pragma unroll
    for (int q = 0; q < 4; q++) {
        int s = sh * 4 + q;
        f32x2 acc = h2f2v(ulH[0][s][pi]);
        f32x2 a1 = h2f2v(ulH[1][s][pi]);
        f32x2 a2 = h2f2v(ulH[2][s][pi]);
        f32x2 a3 = h2f2v(ulH[3][s][pi]);
        acc.x += a1.x + a2.x + a3.x;
        acc.y += a1.y + a2.y + a3.y;
        puH[(base + s) * 128 + pi] = pkh(acc.x, acc.y);
    }
    if (t < NS)
        pda[base + t] = dl[0][t] + dl[1][t] + dl[2][t] + dl[3][t];
}

// ================= per-iter: fin + GRU fused (grid 32x8, 512 thr) ============
__global__ void __launch_bounds__(512)
k_fingru(const unsigned* __restrict__ puH, const float* __restrict__ pda,
         const float* __restrict__ slots,
         const unsigned* __restrict__ w2cH, const unsigned* __restrict__ whhH,
         const float* __restrict__ b2g, const float* __restrict__ bhh,
         float* __restrict__ news) {
    int bb = blockIdx.x, ot = blockIdx.y, t = threadIdx.x;
    __shared__ unsigned AlH[NS][128], SlH[NS][128];
    __shared__ float pp[7][64][24];
    __shared__ float den[NS];
    // den[s] = sum_c pda
    if (t < 64) {
        int s = t & 7, cg = t >> 3;
        float a = 0.f;
#pragma unroll
        for (int c = 0; c < 4; c++)
            a += pda[((size_t)bb * NCHUNK + cg * 4 + c) * NS + s];
        a += DPPF(a, 0x128);
        a = addx16(a);
        a = addx32(a);
        if (t < 8) den[s] = a;
    }
    // SlH pack
#pragma unroll
    for (int k = 0; k < 2; k++) {
        int idx = t + k * 512;
        int rr = idx >> 7, pi2 = idx & 127;
        float2 sv = *(const float2*)&slots[(size_t)bb * 2048 + rr * 256 + 2 * pi2];
        SlH[rr][pi2] = pkh(sv.x, sv.y);
    }
    // raw pu chunk-sums (2 packed indices per thread)
    f32x2 raw[2];
#pragma unroll
    for (int k = 0; k < 2; k++) {
        int idx = t + k * 512;
        int s = idx >> 7, pi2 = idx & 127;
        f32x2 a = {0.f, 0.f};
        const unsigned* src = puH + ((size_t)bb * NCHUNK * NS + s) * 128 + pi2;
#pragma unroll 8
        for (int c = 0; c < NCHUNK; c++) {
            f32x2 v = h2f2v(src[(size_t)c * NS * 128]);
            a.x += v.x; a.y += v.y;
        }
        raw[k] = a;
    }
    __syncthreads();
#pragma unroll
    for (int k = 0; k < 2; k++) {
        int idx = t + k * 512;
        int s = idx >> 7, pi2 = idx & 127;
        float inv = __fdividef(1.f, den[s]);
        AlH[s][pi2] = pkh(raw[k].x * inv, raw[k].y * inv);
    }
    __syncthreads();
    // GRU (4-oc uint4 + fdot2, Ksplit8)
    int q = t & 7, r = (t >> 3) & 7, kp = t >> 6;
    int oc0 = ot * 32 + q * 4;
    float ir[4] = {}, iz[4] = {}, in_[4] = {}, hr[4] = {}, hz[4] = {}, hn[4] = {};
    int p0 = kp * 16;
#pragma unroll 4
    for (int i = 0; i < 16; i++) {
        int ep = p0 + i;
        uint4 w0 = *(const uint4*)&w2cH[(size_t)ep * 768 + oc0];
        uint4 w1 = *(const uint4*)&w2cH[(size_t)ep * 768 + oc0 + 256];
        uint4 w2 = *(const uint4*)&w2cH[(size_t)ep * 768 + oc0 + 512];
        uint4 u0 = *(const uint4*)&whhH[(size_t)ep * 768 + oc0];
        uint4 u1 = *(const uint4*)&whhH[(size_t)ep * 768 + oc0 + 256];
        uint4 u2 = *(const uint4*)&whhH[(size_t)ep * 768 + oc0 + 512];
        unsigned ah = AlH[r][ep], hh = SlH[r][ep];
        const unsigned* w0u = (const unsigned*)&w0;
        const unsigned* w1u = (const unsigned*)&w1;
        const unsigned* w2u = (const unsigned*)&w2;
        const unsigned* u0u = (const unsigned*)&u0;
        const unsigned* u1u = (const unsigned*)&u1;
        const unsigned* u2u = (const unsigned*)&u2;
#pragma unroll
        for (int j = 0; j < 4; j++) {
            ir[j]  = fdot2u(w0u[j], ah, ir[j]);
            iz[j]  = fdot2u(w1u[j], ah, iz[j]);
            in_[j] = fdot2u(w2u[j], ah, in_[j]);
            hr[j]  = fdot2u(u0u[j], hh, hr[j]);
            hz[j]  = fdot2u(u1u[j], hh, hz[j]);
            hn[j]  = fdot2u(u2u[j], hh, hn[j]);
        }
    }
    int slot = (r << 3) | q;
    if (kp) {
        float* d = &pp[kp - 1][slot][0];
#pragma unroll
        for (int j = 0; j < 4; j++) {
            d[j] = ir[j]; d[4 + j] = iz[j]; d[8 + j] = in_[j];
            d[12 + j] = hr[j]; d[16 + j] = hz[j]; d[20 + j] = hn[j];
        }
    }
    __syncthreads();
    if (!kp) {
#pragma unroll
        for (int k = 0; k < 7; k++) {
            const float* s_ = &pp[k][slot][0];
#pragma unroll
            for (int j = 0; j < 4; j++) {
                ir[j] += s_[j]; iz[j] += s_[4 + j]; in_[j] += s_[8 + j];
                hr[j] += s_[12 + j]; hz[j] += s_[16 + j]; hn[j] += s_[20 + j];
            }
        }
        float4 hv = *(const float4*)&slots[((size_t)bb * NS + r) * DIM + oc0];
        float hvv[4] = {hv.x, hv.y, hv.z, hv.w};
        float out[4];
#pragma unroll
        for (int j = 0; j < 4; j++) {
            int oc = oc0 + j;
            float gir = ir[j] + b2g[oc], giz = iz[j] + b2g[oc + 256], gin = in_[j] + b2g[oc + 512];
            float ghr = hr[j] + bhh[oc], ghz = hz[j] + bhh[oc + 256], ghn = hn[j] + bhh[oc + 512];
            float rg = 1.f / (1.f + __expf(-(gir + ghr)));
            float zg = 1.f / (1.f + __expf(-(giz + ghz)));
            float ng = tanhf(fmaf(rg, ghn, gin));
            out[j] = fmaf(zg, hvv[j] - ng, ng);
        }
        *(float4*)&news[((size_t)bb * NS + r) * DIM + oc0] = float4{out[0], out[1], out[2], out[3]};
    }
}

// ================= per-iter: LN(news) + FF1 -> packed h1 =====================
__global__ void __launch_bounds__(512)
k_ff1(const float* __restrict__ news, const unsigned* __restrict__ f1H,
      const float* __restrict__ f1bp, unsigned* __restrict__ h1H) {
    int bb = blockIdx.x, ht = blockIdx.y, t = threadIdx.x;
    int wave = t >> 6, lane = t & 63;
    __shared__ unsigned ZH[NS][128];
    __shared__ float pp[3][128][4];
    {
        float4 xv = *(const float4*)&news[((size_t)bb * NS + wave) * DIM + lane * 4];
        float S, Q;
        tree2(xv.x + xv.y + xv.z + xv.w,
              xv.x * xv.x + xv.y * xv.y + xv.z * xv.z + xv.w * xv.w, lane, S, Q);
        float m = S * (1.f / DIM);
        float rstd = rsqrtf(Q * (1.f / DIM) - m * m + LN_EPS);
        ZH[wave][lane * 2]     = pkh((xv.x - m) * rstd, (xv.y - m) * rstd);
        ZH[wave][lane * 2 + 1] = pkh((xv.z - m) * rstd, (xv.w - m) * rstd);
    }
    __syncthreads();
    int cq = t & 15, r = (t >> 4) & 7, kp = t >> 7;
    int c0 = ht * 64 + cq * 4;
    float acc[4] = {};
    int p0 = kp * 32;
#pragma unroll 4
    for (int i = 0; i < 32; i++) {
        int ep = p0 + i;
        uint4 wv4 = *(const uint4*)&f1H[(size_t)ep * HID + c0];
        unsigned zh = ZH[r][ep];
        const unsigned* wu = (const unsigned*)&wv4;
#pragma unroll
        for (int j = 0; j < 4; j++) acc[j] = fdot2u(wu[j], zh, acc[j]);
    }
    int slot = (r << 4) | cq;
    if (kp) {
        float* d = &pp[kp - 1][slot][0];
#pragma unroll
        for (int j = 0; j < 4; j++) d[j] = acc[j];
    }
    __syncthreads();
    if (!kp) {
#pragma unroll
        for (int k = 0; k < 3; k++) {
            const float* s_ = &pp[k][slot][0];
#pragma unroll
            for (int j = 0; j < 4; j++) acc[j] += s_[j];
        }
        float h0 = fmaxf(acc[0] + f1bp[c0 + 0], 0.f);
        float h1v = fmaxf(acc[1] + f1bp[c0 + 1], 0.f);
        float h2 = fmaxf(acc[2] + f1bp[c0 + 2], 0.f);
        float h3 = fmaxf(acc[3] + f1bp[c0 + 3], 0.f);
        uint2 st;
        st.x = pkh(h0, h1v);
        st.y = pkh(h2, h3);
        *(uint2*)&h1H[((size_t)bb * NS + r) * 256 + c0 / 2] = st;
    }
}

// ================= per-iter: FF2 + residual (4-oc uint4 + fdot2, Ksplit8) ====
__global__ void __launch_bounds__(512)
k_ff2(const unsigned* __restrict__ h1H, const unsigned* __restrict__ f2H,
      const float* __restrict__ f2b, const float* __restrict__ news,
      float* __restrict__ slots) {
    int bb = blockIdx.x, ot = blockIdx.y, t = threadIdx.x;
    __shared__ unsigned HH[NS][256];
    __shared__ float pp[7][64][4];
    for (int idx = t; idx < 512; idx += 512)
        ((uint4*)HH)[idx] = ((const uint4*)(h1H + (size_t)bb * NS * 256))[idx];
    __syncthreads();
    int q = t & 7, r = (t >> 3) & 7, kp = t >> 6;
    int oc0 = ot * 32 + q * 4;
    float acc[4] = {};
    int p0 = kp * 32;
#pragma unroll 4
    for (int i = 0; i < 32; i++) {
        int ep = p0 + i;
        uint4 wv4 = *(const uint4*)&f2H[(size_t)ep * 256 + oc0];
        unsigned hh = HH[r][ep];
        const unsigned* wu = (const unsigned*)&wv4;
#pragma unroll
        for (int j = 0; j < 4; j++) acc[j] = fdot2u(wu[j], hh, acc[j]);
    }
    int slot = (r << 3) | q;
    if (kp) {
        float* d = &pp[kp - 1][slot][0];
#pragma unroll
        for (int j = 0; j < 4; j++) d[j] = acc[j];
    }
    __syncthreads();
    if (!kp) {
#pragma unroll
        for (int k = 0; k < 7; k++) {
            const float* s_ = &pp[k][slot][0];
#pragma unroll
            for (int j = 0; j < 4; j++) acc[j] += s_[j];
        }
        float4 nv = *(const float4*)&news[((size_t)bb * NS + r) * DIM + oc0];
        float4 bv4 = *(const float4*)&f2b[oc0];
        float4 out = {nv.x + acc[0] + bv4.x, nv.y + acc[1] + bv4.y,
                      nv.z + acc[2] + bv4.z, nv.w + acc[3] + bv4.w};
        *(float4*)&slots[((size_t)bb * NS + r) * DIM + oc0] = out;
    }
}

// ================= per-iter: LN(slots) + qk + c2 (4-oc uint4, Ksplit8) =======
__global__ void __launch_bounds__(512)
k_qk2(const float* __restrict__ slots, const unsigned* __restrict__ MppH,
      const float* __restrict__ biasp, const float* __restrict__ u2p,
      float* __restrict__ qkw, float* __restrict__ c2b) {
    int bb = blockIdx.x, ot = blockIdx.y, t = threadIdx.x;
    int wave = t >> 6, lane = t & 63;
    __shared__ unsigned ZH[NS][128];
    __shared__ float pp[7][64][4];
    {
        float4 xv = *(const float4*)&slots[((size_t)bb * NS + wave) * DIM + lane * 4];
        float S, Q;
        tree2(xv.x + xv.y + xv.z + xv.w,
              xv.x * xv.x + xv.y * xv.y + xv.z * xv.z + xv.w * xv.w, lane, S, Q);
        float m = S * (1.f / DIM);
        float rstd = rsqrtf(Q * (1.f / DIM) - m * m + LN_EPS);
        ZH[wave][lane * 2]     = pkh((xv.x - m) * rstd, (xv.y - m) * rstd);
        ZH[wave][lane * 2 + 1] = pkh((xv.z - m) * rstd, (xv.w - m) * rstd);
    }
    __syncthreads();
    int q = t & 7, r = (t >> 3) & 7, kp = t >> 6;
    int oc0 = ot * 32 + q * 4;
    float acc[4] = {};
    int p0 = kp * 16;
#pragma unroll 4
    for (int i = 0; i < 16; i++) {
        int ep = p0 + i;
        uint4 wv4 = *(const uint4*)&MppH[(size_t)ep * 256 + oc0];
        unsigned zh = ZH[r][ep];
        const unsigned* wu = (const unsigned*)&wv4;
#pragma unroll
        for (int j = 0; j < 4; j++) acc[j] = fdot2u(wu[j], zh, acc[j]);
    }
    int slot = (r << 3) | q;
    if (kp) {
        float* d = &pp[kp - 1][slot][0];
#pragma unroll
        for (int j = 0; j < 4; j++) d[j] = acc[j];
    }
    __syncthreads();
    if (!kp) {
#pragma unroll
        for (int k = 0; k < 7; k++) {
            const float* s_ = &pp[k][slot][0];
#pragma unroll
            for (int j = 0; j < 4; j++) acc[j] += s_[j];
        }
        float4 bv4 = *(const float4*)&biasp[oc0];
        float4 out = {acc[0] + bv4.x, acc[1] + bv4.y, acc[2] + bv4.z, acc[3] + bv4.w};
        *(float4*)&qkw[((size_t)bb * NS + r) * DIM + oc0] = out;
    }
    if (ot == 0 && t < 64) {
        int s = t >> 3, j = t & 7;
        float a = 0.f;
        for (int p = j * 16; p < j * 16 + 16; p++) {
            float2 z = h2f2(ZH[s][p]);
            a = fmaf(z.x, u2p[2 * p], fmaf(z.y, u2p[2 * p + 1], a));
        }
        a += DPPF(a, 0xB1);
        a += DPPF(a, 0x4E);
        a += DPPF(a, 0x141);
        if (j == 0) c2b[bb * NS + s] = a + biasp[256];
    }
}

extern "C" void kernel_launch(void* const* d_in, const int* in_sizes, int n_in,
                              void* d_out, int out_size, void* d_ws, size_t ws_size,
                              hipStream_t stream) {
    const float* x     = (const float*)d_in[0];
    const float* noise = (const float*)d_in[1];
    const float* mu  = (const float*)d_in[3];
    const float* sg  = (const float*)d_in[4];
    const float* wq  = (const float*)d_in[5];
    const float* bq  = (const float*)d_in[6];
    const float* wk  = (const float*)d_in[7];
    const float* bk  = (const float*)d_in[8];
    const float* wv  = (const float*)d_in[9];
    const float* bv  = (const float*)d_in[10];
    const float* wih = (const float*)d_in[11];
    const float* whh = (const float*)d_in[12];
    const float* bih = (const float*)d_in[13];
    const float* bhh = (const float*)d_in[14];
    const float* f1w = (const float*)d_in[15];
    const float* f1b = (const float*)d_in[16];
    const float* f2w = (const float*)d_in[17];
    const float* f2b = (const float*)d_in[18];
    const float* liw = (const float*)d_in[19];
    const float* lib = (const float*)d_in[20];
    const float* lsw = (const float*)d_in[21];
    const float* lsb = (const float*)d_in[22];
    const float* lfw = (const float*)d_in[23];
    const float* lfb = (const float*)d_in[24];
    float* slots = (float*)d_out;

    __half* xh = (__half*)d_ws;                         // 64 MB
    float* p = (float*)(xh + (size_t)NB * NTOK * DIM);
    unsigned* MppH = (unsigned*)p; p += 128 * 256;
    unsigned* w2cH = (unsigned*)p; p += 128 * 768;
    unsigned* whhH = (unsigned*)p; p += 128 * 768;
    unsigned* f1H  = (unsigned*)p; p += 128 * 512;
    unsigned* f2H  = (unsigned*)p; p += 256 * 256;
    unsigned* h1H  = (unsigned*)p; p += NROWS * 256;
    unsigned* puH  = (unsigned*)p; p += (size_t)NB * NCHUNK * NS * 128;
    float* u2p   = p; p += 256;
    float* biasp = p; p += 257;
    float* f1bp  = p; p += 512;
    float* b2g   = p; p += 768;
    float* qkw   = p; p += NROWS * 256;
    float* c2b   = p; p += NROWS;
    float* pda   = p; p += NB * NCHUNK * NS;
    float* news  = p; p += NROWS * 256;

    k_pre<<<WP_BLKS, 256, 0, stream>>>(
        wq, wk, bk, bq, lsb, lsw, MppH, u2p, biasp,
        wv, wih, w2cH,
        f1w, f1b, lfb, f1bp,
        bih, bv, b2g,
        whh, f2w, lfw, whhH, f1H, f2H);
    k_iq<<<NB, 512, 0, stream>>>(noise, mu, sg, slots, MppH, biasp, u2p, qkw, c2b);

    for (int it = 0; it < 3; it++) {
        if (it == 0)
            k_attnT<true><<<dim3(NCHUNK, NB), 256, 0, stream>>>(
                x, liw, lib, xh, qkw, c2b, puH, pda);
        else
            k_attnT<false><<<dim3(NCHUNK, NB), 256, 0, stream>>>(
                x, liw, lib, xh, qkw, c2b, puH, pda);
        k_fingru<<<dim3(NB, NS), 512, 0, stream>>>(puH, pda, slots, w2cH, whhH,
                                                   b2g, bhh, news);
        k_ff1<<<dim3(NB, NS), 512, 0, stream>>>(news, f1H, f1bp, h1H);
        k_ff2<<<dim3(NB, NS), 512, 0, stream>>>(h1H, f2H, f2b, news, slots);
        if (it < 2)
            k_qk2<<<dim3(NB, NS), 512, 0, stream>>>(slots, MppH, biasp, u2p, qkw, c2b);
    }
}